// Round 1
// 211.751 us; speedup vs baseline: 1.1377x; 1.1377x over previous
//
#include <hip/hip_runtime.h>
#include <hip/hip_bf16.h>

// Problem constants
#define NB 2
#define SS 2048
#define EE 1024
#define HH 16
#define DD 64
#define NHD (NB*HH)   // 32 (n,h) pairs
#define KT 64         // keys per flash tile

// fold softmax scale (1/sqrt(1024)) and log2(e) into Q' so P = exp2(S')
#define QSCALE 0.04508422002777998f

typedef _Float16 half8 __attribute__((ext_vector_type(8)));
typedef _Float16 half4 __attribute__((ext_vector_type(4)));
typedef float floatx4 __attribute__((ext_vector_type(4)));

__device__ __forceinline__ half8 cvt8(const float* p) {
    float4 x = *(const float4*)p;
    float4 y = *(const float4*)(p + 4);
    half8 h = { (_Float16)x.x, (_Float16)x.y, (_Float16)x.z, (_Float16)x.w,
                (_Float16)y.x, (_Float16)y.y, (_Float16)y.z, (_Float16)y.w };
    return h;
}

// XOR-swizzled index (in halves) for a [64-row][64-half] f16 LDS tile.
// 16B groups: group' = group ^ (row&7). Keeps b128 alignment (pad can't),
// saves the +8 pad -> attn LDS drops 45KB -> 40KB = 4 blocks/CU.
// All accesses are >=8B aligned within a group; write/read use the same
// (row, col) pair so the permutation is consistent (both-sides rule).
__device__ __forceinline__ int swz64(int row, int colh) {
    return (row << 6) + ((((colh >> 3) ^ (row & 7)) << 3) | (colh & 7));
}

// ---------------------------------------------------------------------------
// Kernel 1 (r13): QKV projection via MFMA. GEMM M=65536,K=64,N=64 x3.
// Row remap vs r12: block = one (n,h) x 64 consecutive s (M-rows are
// independent, so any block->row mapping is legal). This makes the V
// transpose LDS-local: stage the 64x64 V tile in LDS, store Vt coalesced
// (32B/lane) instead of r12's 4.2M scattered 2B stores at 4KB stride.
// Outputs: Q' f16 [nh][s][d] pre-scaled, K' f16 [nh][s][d], V' f16 [nh][d][s].
// ---------------------------------------------------------------------------
__global__ __launch_bounds__(256) void proj_kernel(
    const float* __restrict__ Q, const float* __restrict__ K, const float* __restrict__ V,
    const float* __restrict__ Wq, const float* __restrict__ Wk, const float* __restrict__ Wv,
    _Float16* __restrict__ Qp, _Float16* __restrict__ Kp, _Float16* __restrict__ Vt)
{
    int t = threadIdx.x, lane = t & 63, wid = t >> 6;
    int lr = lane & 15, lg = lane >> 4;
    int b = blockIdx.x;             // 0..1023
    int nh = b >> 5, st = b & 31;   // head-pair, s-tile (64 rows)
    int n = nh >> 4, h = nh & 15;

    __shared__ __align__(16) _Float16 vt[DD][72];   // 9 KB transpose buffer

    // A-fragment rows: s = st*64 + wid*16 + lr  (m = lane&15)
    const size_t xoff = ((size_t)n * SS + st * 64 + wid * 16 + lr) * EE
                        + (size_t)h * DD + lg * 8;
    // C rows: s = st*64 + wid*16 + lg*4 + r
    const size_t qob = ((size_t)nh * SS + st * 64 + wid * 16 + lg * 4) * DD;

    const float* tens[3] = {Q, K, V};
    const float* wts[3]  = {Wq, Wk, Wv};

    #pragma unroll
    for (int x = 0; x < 3; ++x) {
        const float* Xr = tens[x] + xoff;
        half8 a0 = cvt8(Xr);
        half8 a1 = cvt8(Xr + 32);
        floatx4 acc[4];
        #pragma unroll
        for (int ns = 0; ns < 4; ++ns) {
            const float* Wr = wts[x] + (size_t)(ns * 16 + lr) * DD + lg * 8;
            half8 b0 = cvt8(Wr);
            half8 b1 = cvt8(Wr + 32);
            floatx4 c = (floatx4){0.f, 0.f, 0.f, 0.f};
            c = __builtin_amdgcn_mfma_f32_16x16x32_f16(a0, b0, c, 0, 0, 0);
            c = __builtin_amdgcn_mfma_f32_16x16x32_f16(a1, b1, c, 0, 0, 0);
            acc[ns] = c;
        }
        if (x == 0) {
            #pragma unroll
            for (int ns = 0; ns < 4; ++ns)
                #pragma unroll
                for (int r = 0; r < 4; ++r)
                    Qp[qob + (size_t)r * DD + ns * 16 + lr] = (_Float16)(acc[ns][r] * QSCALE);
        } else if (x == 1) {
            #pragma unroll
            for (int ns = 0; ns < 4; ++ns)
                #pragma unroll
                for (int r = 0; r < 4; ++r)
                    Kp[qob + (size_t)r * DD + ns * 16 + lr] = (_Float16)acc[ns][r];
        } else {
            // transpose in LDS: vt[d][s_local], d = ns*16+lr, s_local = wid*16+lg*4+r
            #pragma unroll
            for (int ns = 0; ns < 4; ++ns)
                #pragma unroll
                for (int r = 0; r < 4; ++r)
                    vt[ns * 16 + lr][wid * 16 + lg * 4 + r] = (_Float16)acc[ns][r];
        }
    }
    __syncthreads();
    // coalesced Vt store: thread t covers d = t>>2, 32 contiguous bytes of s.
    {
        int d = t >> 2, q4 = (t & 3) * 16;
        _Float16* dst = Vt + ((size_t)nh * DD + d) * SS + st * 64 + q4;
        *(half8*)dst       = *(const half8*)(&vt[d][q4]);
        *(half8*)(dst + 8) = *(const half8*)(&vt[d][q4 + 8]);
    }
}

// ---------------------------------------------------------------------------
// Kernel 2 (r13): flash MFMA attention, LDS-staged K/V tiles.
// r12 at 90.5us: MfmaUtil 16%, HBM 2.9% -> latency-bound. LDS 45KB capped
// residency at 3 blocks/CU against a 4-block/CU grid (Occupancy 24.7%,
// tail dispatch wave at 1/4 machine). r13: replace +8 pad with 16B-group
// XOR swizzle -> kbuf/vbuf/plds = 16+16+8 = 40KB exactly -> 4 blocks/CU,
// 16 waves/CU, single clean dispatch wave. Swizzle keeps every b128
// fragment access at the 8-pass wave64 minimum (8 lanes per 4-bank group).
// Fragment maps (m89/m120-verified): A/B[m][k]: m=lane&15, k=(lane>>4)*8+j.
// C/D[row][col]: col=lane&15, row=(lane>>4)*4+reg.
// GRID: 1024 = 32 nh x 32 q-tiles.
// ---------------------------------------------------------------------------
__global__ __launch_bounds__(256, 4) void attn_kernel(
    const _Float16* __restrict__ Qp, const _Float16* __restrict__ Kp,
    const _Float16* __restrict__ Vt, _Float16* __restrict__ Of)
{
    int b = blockIdx.x;                  // 0..1023
    int slot = b >> 3;                   // 0..127
    int nh = (b & 7) * 4 + (slot & 3);   // XCD swizzle: 4 heads per XCD in L2
    int qt = slot >> 2;                  // 0..31 (64-row q tile)
    int n = nh >> 4, h = nh & 15;
    int t = threadIdx.x;
    int lane = t & 63, wid = t >> 6;
    int lr = lane & 15;        // fragment row index / C col (= q here)
    int lg = lane >> 4;        // fragment k-group / C row-group

    __shared__ __align__(16) _Float16 kbuf[2][KT * DD];   // 2 x 8 KB, swizzled
    __shared__ __align__(16) _Float16 vbuf[2][DD * KT];   // 2 x 8 KB, swizzled
    __shared__ __align__(16) _Float16 plds[4][16 * 64];   // 8 KB, swizzled

    const _Float16* Qb = Qp + ((size_t)nh * SS + qt * 64 + wid * 16) * DD;
    const _Float16* Kb = Kp + (size_t)nh * SS * DD;
    const _Float16* Vb = Vt + (size_t)nh * DD * SS;

    // Q B-fragments, loaded once: n=q=lr, k=d = c*32 + lg*8 + j
    half8 qf0 = *(const half8*)(Qb + (size_t)lr * DD + lg * 8);
    half8 qf1 = *(const half8*)(Qb + (size_t)lr * DD + 32 + lg * 8);

    // staging map: slot s in [0,512): row = s>>3, colg = s&7 (8 half8s/row)
    int sr = t >> 3, sc = (t & 7) * 8;

    // ---- prologue: stage tile kb=0 into buffer 0
    {
        half8 k0 = *(const half8*)(Kb + (size_t)sr * DD + sc);
        half8 k1 = *(const half8*)(Kb + (size_t)(sr + 32) * DD + sc);
        half8 v0 = *(const half8*)(Vb + (size_t)sr * SS + sc);
        half8 v1 = *(const half8*)(Vb + (size_t)(sr + 32) * SS + sc);
        *(half8*)(&kbuf[0][swz64(sr, sc)]) = k0;
        *(half8*)(&kbuf[0][swz64(sr + 32, sc)]) = k1;
        *(half8*)(&vbuf[0][swz64(sr, sc)]) = v0;
        *(half8*)(&vbuf[0][swz64(sr + 32, sc)]) = v1;
    }
    __syncthreads();

    floatx4 oacc[4];
    #pragma unroll
    for (int ns = 0; ns < 4; ++ns) oacc[ns] = (floatx4){0.f, 0.f, 0.f, 0.f};
    float lsumF = 0.f;   // partial row sum for q = lr (this lane's keys)

    int p = 0;
    for (int kb = 0; kb < SS; kb += KT, p ^= 1) {
        // ---- issue global loads for tile t+1 (wrap at end: dummy, unused)
        int kn = (kb + KT) & (SS - 1);
        half8 sk0 = *(const half8*)(Kb + (size_t)(kn + sr) * DD + sc);
        half8 sk1 = *(const half8*)(Kb + (size_t)(kn + sr + 32) * DD + sc);
        half8 sv0 = *(const half8*)(Vb + (size_t)sr * SS + kn + sc);
        half8 sv1 = *(const half8*)(Vb + (size_t)(sr + 32) * SS + kn + sc);

        // ---- K A-fragments from LDS (m=key rows): kbuf[key][d]
        half8 kf[4][2];
        #pragma unroll
        for (int ns = 0; ns < 4; ++ns) {
            kf[ns][0] = *(const half8*)(&kbuf[p][swz64(ns * 16 + lr, lg * 8)]);
            kf[ns][1] = *(const half8*)(&kbuf[p][swz64(ns * 16 + lr, 32 + lg * 8)]);
        }
        // ---- S^T = K Q^T : D[key][q]
        floatx4 sc_[4];
        #pragma unroll
        for (int ns = 0; ns < 4; ++ns) {
            floatx4 c = (floatx4){0.f, 0.f, 0.f, 0.f};
            c = __builtin_amdgcn_mfma_f32_16x16x32_f16(kf[ns][0], qf0, c, 0, 0, 0);
            c = __builtin_amdgcn_mfma_f32_16x16x32_f16(kf[ns][1], qf1, c, 0, 0, 0);
            sc_[ns] = c;
        }
        // ---- V B-fragments from LDS: vbuf[d][key]
        half8 vf[4][2];
        #pragma unroll
        for (int ns = 0; ns < 4; ++ns) {
            vf[ns][0] = *(const half8*)(&vbuf[p][swz64(ns * 16 + lr, lg * 8)]);
            vf[ns][1] = *(const half8*)(&vbuf[p][swz64(ns * 16 + lr, 32 + lg * 8)]);
        }
        // ---- P = exp2(S^T); per-lane row-sum; packed b64 store per subtile.
        // Lane holds P[q=lr][key = ns*16 + lg*4 + r], r=0..3 contiguous.
        #pragma unroll
        for (int ns = 0; ns < 4; ++ns) {
            float p0 = exp2f(fminf(sc_[ns][0], 50.f));
            float p1 = exp2f(fminf(sc_[ns][1], 50.f));
            float p2 = exp2f(fminf(sc_[ns][2], 50.f));
            float p3 = exp2f(fminf(sc_[ns][3], 50.f));
            lsumF += (p0 + p1) + (p2 + p3);
            half4 v = { (_Float16)p0, (_Float16)p1, (_Float16)p2, (_Float16)p3 };
            *(half4*)(&plds[wid][swz64(lr, ns * 16 + lg * 4)]) = v;
        }
        // wave-local DS drain: P stores visible to this wave's lanes
        asm volatile("s_waitcnt lgkmcnt(0)" ::: "memory");
        // ---- P A-fragments (m=q=lr, k=key = c*32 + lg*8 + j)
        half8 pf0 = *(const half8*)(&plds[wid][swz64(lr, lg * 8)]);
        half8 pf1 = *(const half8*)(&plds[wid][swz64(lr, 32 + lg * 8)]);
        // ---- O += P V
        #pragma unroll
        for (int ns = 0; ns < 4; ++ns) {
            oacc[ns] = __builtin_amdgcn_mfma_f32_16x16x32_f16(pf0, vf[ns][0], oacc[ns], 0, 0, 0);
            oacc[ns] = __builtin_amdgcn_mfma_f32_16x16x32_f16(pf1, vf[ns][1], oacc[ns], 0, 0, 0);
        }
        // ---- write staged tile t+1 into the other buffer, then barrier
        // (the barrier also orders this iter's plds reads before next iter's
        //  plds writes -> single plds buffer is safe)
        *(half8*)(&kbuf[p ^ 1][swz64(sr, sc)]) = sk0;
        *(half8*)(&kbuf[p ^ 1][swz64(sr + 32, sc)]) = sk1;
        *(half8*)(&vbuf[p ^ 1][swz64(sr, sc)]) = sv0;
        *(half8*)(&vbuf[p ^ 1][swz64(sr + 32, sc)]) = sv1;
        __syncthreads();
    }

    // ---- finalize row sums: lane's partial covers its lg; sum across quads
    float s = lsumF;
    s += __shfl_xor(s, 16, 64);
    s += __shfl_xor(s, 32, 64);
    // s = full row sum for q = lr (replicated across quads).
    float linv[4];
    #pragma unroll
    for (int r = 0; r < 4; ++r)
        linv[r] = 1.f / __shfl(s, lg * 4 + r, 64);

    // ---- write O (f16, [n][s][e]): row q = lg*4+r, col = h*64 + ns*16 + lr
    _Float16* Ob = Of + ((size_t)n * SS + qt * 64 + wid * 16) * EE + h * DD;
    #pragma unroll
    for (int ns = 0; ns < 4; ++ns)
        #pragma unroll
        for (int r = 0; r < 4; ++r)
            Ob[(size_t)(lg * 4 + r) * EE + ns * 16 + lr] = (_Float16)(oacc[ns][r] * linv[r]);
}

// ---------------------------------------------------------------------------
// Kernel 2b: Wo f32 -> f16 (layout preserved = native B-fragment layout).
// ---------------------------------------------------------------------------
__global__ __launch_bounds__(256) void wconv_kernel(
    const float* __restrict__ W, _Float16* __restrict__ Wf)
{
    int i = (blockIdx.x * 256 + threadIdx.x) * 8;
    *(half8*)(Wf + i) = cvt8(W + i);
}

// ---------------------------------------------------------------------------
// Kernel 3 (r12, unchanged): out = O @ Wo.T + bo, 128x128-tile MFMA GEMM.
// 256 blocks (1/CU) = 32 m-tiles x 8 n-tiles (b&7 pins one n-tile = 256 KB
// of Wf per XCD L2). Block stages A[128][64] + B[128][64] (stride 72:
// aligned b128, 2-way banks), double-buffered, one barrier per k-chunk.
// ---------------------------------------------------------------------------
__global__ __launch_bounds__(256, 1) void oproj_kernel(
    const _Float16* __restrict__ Of, const _Float16* __restrict__ Wf,
    const float* __restrict__ bo, float* __restrict__ out)
{
    int b = blockIdx.x;             // 0..255
    int nb = b & 7, mb = b >> 3;
    int t = threadIdx.x, lane = t & 63, wid = t >> 6;
    int wm = wid >> 1, wn = wid & 1;
    int lr = lane & 15, lg = lane >> 4;
    int m0 = mb * 128, n0 = nb * 128;

    __shared__ __align__(16) _Float16 As[2][128][72];   // 2 x 18 KB
    __shared__ __align__(16) _Float16 Bs[2][128][72];   // 2 x 18 KB

    // staging map: thread t covers row t>>1 (0..127), 4 half8s at col (t&1)*32
    int srow = t >> 1, scol = (t & 1) * 32;
    const _Float16* Ag = Of + (size_t)(m0 + srow) * EE + scol;
    const _Float16* Bg = Wf + (size_t)(n0 + srow) * EE + scol;

    floatx4 acc[4][4];
    #pragma unroll
    for (int sm = 0; sm < 4; ++sm)
        #pragma unroll
        for (int sn = 0; sn < 4; ++sn) acc[sm][sn] = (floatx4){0.f, 0.f, 0.f, 0.f};

    // ---- prologue: stage kb=0 into buffer 0
    #pragma unroll
    for (int j = 0; j < 4; ++j) {
        *(half8*)(&As[0][srow][scol + j * 8]) = *(const half8*)(Ag + j * 8);
        *(half8*)(&Bs[0][srow][scol + j * 8]) = *(const half8*)(Bg + j * 8);
    }
    __syncthreads();

    int p = 0;
    for (int kb = 0; kb < EE; kb += 64, p ^= 1) {
        int kn = kb + 64;
        // ---- issue next chunk's global loads
        half8 sa[4], sb[4];
        if (kn < EE) {
            #pragma unroll
            for (int j = 0; j < 4; ++j) {
                sa[j] = *(const half8*)(Ag + kn + j * 8);
                sb[j] = *(const half8*)(Bg + kn + j * 8);
            }
        }
        // ---- compute on buffer p: 2 k-subchunks of 32
        #pragma unroll
        for (int kk = 0; kk < 2; ++kk) {
            half8 af[4], bf[4];
            #pragma unroll
            for (int s = 0; s < 4; ++s) {
                af[s] = *(const half8*)(&As[p][wm * 64 + s * 16 + lr][kk * 32 + lg * 8]);
                bf[s] = *(const half8*)(&Bs[p][wn * 64 + s * 16 + lr][kk * 32 + lg * 8]);
            }
            #pragma unroll
            for (int sm = 0; sm < 4; ++sm)
                #pragma unroll
                for (int sn = 0; sn < 4; ++sn)
                    acc[sm][sn] = __builtin_amdgcn_mfma_f32_16x16x32_f16(
                        af[sm], bf[sn], acc[sm][sn], 0, 0, 0);
        }
        // ---- write staged chunk into the other buffer
        if (kn < EE) {
            #pragma unroll
            for (int j = 0; j < 4; ++j) {
                *(half8*)(&As[p ^ 1][srow][scol + j * 8]) = sa[j];
                *(half8*)(&Bs[p ^ 1][srow][scol + j * 8]) = sb[j];
            }
        }
        __syncthreads();
    }

    // ---- epilogue: C/D col = lr (n), row = lg*4+r (m)
    #pragma unroll
    for (int sn = 0; sn < 4; ++sn) {
        int nn = n0 + wn * 64 + sn * 16 + lr;
        float bn = bo[nn];
        #pragma unroll
        for (int sm = 0; sm < 4; ++sm) {
            #pragma unroll
            for (int r = 0; r < 4; ++r)
                out[(size_t)(m0 + wm * 64 + sm * 16 + lg * 4 + r) * EE + nn]
                    = acc[sm][sn][r] + bn;
        }
    }
}

// ---------------------------------------------------------------------------
extern "C" void kernel_launch(void* const* d_in, const int* in_sizes, int n_in,
                              void* d_out, int out_size, void* d_ws, size_t ws_size,
                              hipStream_t stream)
{
    const float* Q  = (const float*)d_in[0];
    const float* K  = (const float*)d_in[1];
    const float* V  = (const float*)d_in[2];
    const float* Wq = (const float*)d_in[3];
    const float* Wk = (const float*)d_in[4];
    const float* Wv = (const float*)d_in[5];
    const float* Wo = (const float*)d_in[6];
    const float* bo = (const float*)d_in[7];
    float* out = (float*)d_out;

    const size_t NSE = (size_t)NB * SS * EE;   // 4.19M elements
    _Float16* Qp = (_Float16*)d_ws;  // [nh][s][d] pre-scaled   8.4 MB
    _Float16* Kp = Qp + NSE;         // [nh][s][d]              8.4 MB
    _Float16* Vt = Kp + NSE;         // [nh][d][s] transposed   8.4 MB
    _Float16* Of = Vt + NSE;         // [n][s][e] f16           8.4 MB
    _Float16* Wf = Of + NSE;         // [1024][1024] f16        2.1 MB (~36 MB)

    proj_kernel<<<1024, 256, 0, stream>>>(Q, K, V, Wq, Wk, Wv, Qp, Kp, Vt);
    wconv_kernel<<<(EE * EE) / (256 * 8), 256, 0, stream>>>(Wo, Wf);
    attn_kernel<<<NHD * (SS / 64), 256, 0, stream>>>(Qp, Kp, Vt, Of);  // 1024
    oproj_kernel<<<256, 256, 0, stream>>>(Of, Wf, bo, out);
}

// Round 3
// 207.919 us; speedup vs baseline: 1.1586x; 1.0184x over previous
//
#include <hip/hip_runtime.h>
#include <hip/hip_bf16.h>

// Problem constants
#define NB 2
#define SS 2048
#define EE 1024
#define HH 16
#define DD 64
#define NHD (NB*HH)   // 32 (n,h) pairs
#define KT 64         // keys per flash tile

// fold softmax scale (1/sqrt(1024)) and log2(e) into Q' so P = exp2(S')
#define QSCALE 0.04508422002777998f

typedef _Float16 half8 __attribute__((ext_vector_type(8)));
typedef _Float16 half4 __attribute__((ext_vector_type(4)));
typedef float floatx4 __attribute__((ext_vector_type(4)));

__device__ __forceinline__ half8 cvt8(const float* p) {
    float4 x = *(const float4*)p;
    float4 y = *(const float4*)(p + 4);
    half8 h = { (_Float16)x.x, (_Float16)x.y, (_Float16)x.z, (_Float16)x.w,
                (_Float16)y.x, (_Float16)y.y, (_Float16)y.z, (_Float16)y.w };
    return h;
}

// packed f32x2 -> f16x2 (RTZ) returning raw u32
__device__ __forceinline__ unsigned int pkrtz_u32(float a, float b) {
    return __builtin_bit_cast(unsigned int, __builtin_amdgcn_cvt_pkrtz(a, b));
}

// XOR-swizzled index (in halves) for a [64-row][64-half] f16 LDS tile.
// 16B groups: group' = group ^ (row&7). Keeps b128 alignment, LDS = exact
// 40KB in attn -> 4 blocks/CU (r13-verified: occupancy 24.7->31.4).
__device__ __forceinline__ int swz64(int row, int colh) {
    return (row << 6) + ((((colh >> 3) ^ (row & 7)) << 3) | (colh & 7));
}

// ---------------------------------------------------------------------------
// Kernel 1 (r13, unchanged): QKV projection via MFMA. Block = one (n,h) x 64
// consecutive s; V transposed through LDS -> coalesced 32B Vt stores.
// Outputs: Q' f16 [nh][s][d] pre-scaled, K' f16 [nh][s][d], V' f16 [nh][d][s].
// ---------------------------------------------------------------------------
__global__ __launch_bounds__(256) void proj_kernel(
    const float* __restrict__ Q, const float* __restrict__ K, const float* __restrict__ V,
    const float* __restrict__ Wq, const float* __restrict__ Wk, const float* __restrict__ Wv,
    _Float16* __restrict__ Qp, _Float16* __restrict__ Kp, _Float16* __restrict__ Vt)
{
    int t = threadIdx.x, lane = t & 63, wid = t >> 6;
    int lr = lane & 15, lg = lane >> 4;
    int b = blockIdx.x;             // 0..1023
    int nh = b >> 5, st = b & 31;   // head-pair, s-tile (64 rows)
    int n = nh >> 4, h = nh & 15;

    __shared__ __align__(16) _Float16 vt[DD][72];   // 9 KB transpose buffer

    // A-fragment rows: s = st*64 + wid*16 + lr  (m = lane&15)
    const size_t xoff = ((size_t)n * SS + st * 64 + wid * 16 + lr) * EE
                        + (size_t)h * DD + lg * 8;
    // C rows: s = st*64 + wid*16 + lg*4 + r
    const size_t qob = ((size_t)nh * SS + st * 64 + wid * 16 + lg * 4) * DD;

    const float* tens[3] = {Q, K, V};
    const float* wts[3]  = {Wq, Wk, Wv};

    #pragma unroll
    for (int x = 0; x < 3; ++x) {
        const float* Xr = tens[x] + xoff;
        half8 a0 = cvt8(Xr);
        half8 a1 = cvt8(Xr + 32);
        floatx4 acc[4];
        #pragma unroll
        for (int ns = 0; ns < 4; ++ns) {
            const float* Wr = wts[x] + (size_t)(ns * 16 + lr) * DD + lg * 8;
            half8 b0 = cvt8(Wr);
            half8 b1 = cvt8(Wr + 32);
            floatx4 c = (floatx4){0.f, 0.f, 0.f, 0.f};
            c = __builtin_amdgcn_mfma_f32_16x16x32_f16(a0, b0, c, 0, 0, 0);
            c = __builtin_amdgcn_mfma_f32_16x16x32_f16(a1, b1, c, 0, 0, 0);
            acc[ns] = c;
        }
        if (x == 0) {
            #pragma unroll
            for (int ns = 0; ns < 4; ++ns)
                #pragma unroll
                for (int r = 0; r < 4; ++r)
                    Qp[qob + (size_t)r * DD + ns * 16 + lr] = (_Float16)(acc[ns][r] * QSCALE);
        } else if (x == 1) {
            #pragma unroll
            for (int ns = 0; ns < 4; ++ns)
                #pragma unroll
                for (int r = 0; r < 4; ++r)
                    Kp[qob + (size_t)r * DD + ns * 16 + lr] = (_Float16)acc[ns][r];
        } else {
            // transpose in LDS: vt[d][s_local], d = ns*16+lr, s_local = wid*16+lg*4+r
            #pragma unroll
            for (int ns = 0; ns < 4; ++ns)
                #pragma unroll
                for (int r = 0; r < 4; ++r)
                    vt[ns * 16 + lr][wid * 16 + lg * 4 + r] = (_Float16)acc[ns][r];
        }
    }
    __syncthreads();
    // coalesced Vt store: thread t covers d = t>>2, 32 contiguous bytes of s.
    {
        int d = t >> 2, q4 = (t & 3) * 16;
        _Float16* dst = Vt + ((size_t)nh * DD + d) * SS + st * 64 + q4;
        *(half8*)dst       = *(const half8*)(&vt[d][q4]);
        *(half8*)(dst + 8) = *(const half8*)(&vt[d][q4 + 8]);
    }
}

// ---------------------------------------------------------------------------
// Kernel 2 (r14): flash MFMA attention.
// r13 landed 78.8us: MfmaUtil 18.4 / VALUBusy 59.8 = 3.3:1 -> VALU-issue
// bound. Per-iter VALU ~270cyc vs MFMA ~77cyc. r14 cuts reducible VALU:
//  (a) row-sum via MFMA ones-trick: sacc = mfma(pf, ones, sacc); every D
//      column = row sum. Kills 16 f32 adds/iter + epilogue shfl reduce;
//      denominator is now the sum of the SAME f16-rounded P used in PV
//      (common-mode rounding cancels in the weighted average).
//  (b) v_cvt_pkrtz (packed RTZ) for P f32->f16: 8 ops instead of 16 RTN
//      cvts (compiler can't legally emit pkrtz for (_Float16) casts).
// Fragment maps (m89/m120-verified): A/B[m][k]: m=lane&15, k=(lane>>4)*8+j.
// C/D[row][col]: col=lane&15, row=(lane>>4)*4+reg.
// GRID: 1024 = 32 nh x 32 q-tiles. LDS 40KB -> 4 blocks/CU.
// ---------------------------------------------------------------------------
__global__ __launch_bounds__(256, 4) void attn_kernel(
    const _Float16* __restrict__ Qp, const _Float16* __restrict__ Kp,
    const _Float16* __restrict__ Vt, _Float16* __restrict__ Of)
{
    int b = blockIdx.x;                  // 0..1023
    int slot = b >> 3;                   // 0..127
    int nh = (b & 7) * 4 + (slot & 3);   // XCD swizzle: 4 heads per XCD in L2
    int qt = slot >> 2;                  // 0..31 (64-row q tile)
    int n = nh >> 4, h = nh & 15;
    int t = threadIdx.x;
    int lane = t & 63, wid = t >> 6;
    int lr = lane & 15;        // fragment row index / C col (= q here)
    int lg = lane >> 4;        // fragment k-group / C row-group

    __shared__ __align__(16) _Float16 kbuf[2][KT * DD];   // 2 x 8 KB, swizzled
    __shared__ __align__(16) _Float16 vbuf[2][DD * KT];   // 2 x 8 KB, swizzled
    __shared__ __align__(16) _Float16 plds[4][16 * 64];   // 8 KB, swizzled

    const _Float16* Qb = Qp + ((size_t)nh * SS + qt * 64 + wid * 16) * DD;
    const _Float16* Kb = Kp + (size_t)nh * SS * DD;
    const _Float16* Vb = Vt + (size_t)nh * DD * SS;

    // Q B-fragments, loaded once: n=q=lr, k=d = c*32 + lg*8 + j
    half8 qf0 = *(const half8*)(Qb + (size_t)lr * DD + lg * 8);
    half8 qf1 = *(const half8*)(Qb + (size_t)lr * DD + 32 + lg * 8);

    // ones B-fragment for the row-sum MFMA
    half8 ones = { (_Float16)1.f, (_Float16)1.f, (_Float16)1.f, (_Float16)1.f,
                   (_Float16)1.f, (_Float16)1.f, (_Float16)1.f, (_Float16)1.f };

    // staging map: slot s in [0,512): row = s>>3, colg = s&7 (8 half8s/row)
    int sr = t >> 3, sc = (t & 7) * 8;

    // ---- prologue: stage tile kb=0 into buffer 0
    {
        half8 k0 = *(const half8*)(Kb + (size_t)sr * DD + sc);
        half8 k1 = *(const half8*)(Kb + (size_t)(sr + 32) * DD + sc);
        half8 v0 = *(const half8*)(Vb + (size_t)sr * SS + sc);
        half8 v1 = *(const half8*)(Vb + (size_t)(sr + 32) * SS + sc);
        *(half8*)(&kbuf[0][swz64(sr, sc)]) = k0;
        *(half8*)(&kbuf[0][swz64(sr + 32, sc)]) = k1;
        *(half8*)(&vbuf[0][swz64(sr, sc)]) = v0;
        *(half8*)(&vbuf[0][swz64(sr + 32, sc)]) = v1;
    }
    __syncthreads();

    floatx4 oacc[4];
    #pragma unroll
    for (int ns = 0; ns < 4; ++ns) oacc[ns] = (floatx4){0.f, 0.f, 0.f, 0.f};
    floatx4 sacc = (floatx4){0.f, 0.f, 0.f, 0.f};   // row sums via ones-MFMA

    int p = 0;
    for (int kb = 0; kb < SS; kb += KT, p ^= 1) {
        // ---- issue global loads for tile t+1 (wrap at end: dummy, unused)
        int kn = (kb + KT) & (SS - 1);
        half8 sk0 = *(const half8*)(Kb + (size_t)(kn + sr) * DD + sc);
        half8 sk1 = *(const half8*)(Kb + (size_t)(kn + sr + 32) * DD + sc);
        half8 sv0 = *(const half8*)(Vb + (size_t)sr * SS + kn + sc);
        half8 sv1 = *(const half8*)(Vb + (size_t)(sr + 32) * SS + kn + sc);

        // ---- K A-fragments from LDS (m=key rows): kbuf[key][d]
        half8 kf[4][2];
        #pragma unroll
        for (int ns = 0; ns < 4; ++ns) {
            kf[ns][0] = *(const half8*)(&kbuf[p][swz64(ns * 16 + lr, lg * 8)]);
            kf[ns][1] = *(const half8*)(&kbuf[p][swz64(ns * 16 + lr, 32 + lg * 8)]);
        }
        // ---- S^T = K Q^T : D[key][q]
        floatx4 sc_[4];
        #pragma unroll
        for (int ns = 0; ns < 4; ++ns) {
            floatx4 c = (floatx4){0.f, 0.f, 0.f, 0.f};
            c = __builtin_amdgcn_mfma_f32_16x16x32_f16(kf[ns][0], qf0, c, 0, 0, 0);
            c = __builtin_amdgcn_mfma_f32_16x16x32_f16(kf[ns][1], qf1, c, 0, 0, 0);
            sc_[ns] = c;
        }
        // ---- V B-fragments from LDS: vbuf[d][key]
        half8 vf[4][2];
        #pragma unroll
        for (int ns = 0; ns < 4; ++ns) {
            vf[ns][0] = *(const half8*)(&vbuf[p][swz64(ns * 16 + lr, lg * 8)]);
            vf[ns][1] = *(const half8*)(&vbuf[p][swz64(ns * 16 + lr, 32 + lg * 8)]);
        }
        // ---- P = exp2(S^T), packed RTZ to f16, b64 store per subtile.
        // Lane holds P[q=lr][key = ns*16 + lg*4 + r], r=0..3 contiguous.
        #pragma unroll
        for (int ns = 0; ns < 4; ++ns) {
            float p0 = exp2f(fminf(sc_[ns][0], 50.f));
            float p1 = exp2f(fminf(sc_[ns][1], 50.f));
            float p2 = exp2f(fminf(sc_[ns][2], 50.f));
            float p3 = exp2f(fminf(sc_[ns][3], 50.f));
            uint2 pr;
            pr.x = pkrtz_u32(p0, p1);
            pr.y = pkrtz_u32(p2, p3);
            *(uint2*)(&plds[wid][swz64(lr, ns * 16 + lg * 4)]) = pr;
        }
        // wave-local DS drain: P stores visible to this wave's lanes
        asm volatile("s_waitcnt lgkmcnt(0)" ::: "memory");
        // ---- P A-fragments (m=q=lr, k=key = c*32 + lg*8 + j)
        half8 pf0 = *(const half8*)(&plds[wid][swz64(lr, lg * 8)]);
        half8 pf1 = *(const half8*)(&plds[wid][swz64(lr, 32 + lg * 8)]);
        // ---- O += P V ; row-sum += P * ones (matrix pipe, frees VALU)
        #pragma unroll
        for (int ns = 0; ns < 4; ++ns) {
            oacc[ns] = __builtin_amdgcn_mfma_f32_16x16x32_f16(pf0, vf[ns][0], oacc[ns], 0, 0, 0);
            oacc[ns] = __builtin_amdgcn_mfma_f32_16x16x32_f16(pf1, vf[ns][1], oacc[ns], 0, 0, 0);
        }
        sacc = __builtin_amdgcn_mfma_f32_16x16x32_f16(pf0, ones, sacc, 0, 0, 0);
        sacc = __builtin_amdgcn_mfma_f32_16x16x32_f16(pf1, ones, sacc, 0, 0, 0);
        // ---- write staged tile t+1 into the other buffer, then barrier
        // (the barrier also orders this iter's plds reads before next iter's
        //  plds writes -> single plds buffer is safe)
        *(half8*)(&kbuf[p ^ 1][swz64(sr, sc)]) = sk0;
        *(half8*)(&kbuf[p ^ 1][swz64(sr + 32, sc)]) = sk1;
        *(half8*)(&vbuf[p ^ 1][swz64(sr, sc)]) = sv0;
        *(half8*)(&vbuf[p ^ 1][swz64(sr + 32, sc)]) = sv1;
        __syncthreads();
    }

    // ---- normalization: sacc row layout (lg*4+r) matches oacc rows exactly.
    float linv[4];
    #pragma unroll
    for (int r = 0; r < 4; ++r)
        linv[r] = 1.f / sacc[r];

    // ---- write O (f16, [n][s][e]): row q = lg*4+r, col = h*64 + ns*16 + lr
    _Float16* Ob = Of + ((size_t)n * SS + qt * 64 + wid * 16) * EE + h * DD;
    #pragma unroll
    for (int ns = 0; ns < 4; ++ns)
        #pragma unroll
        for (int r = 0; r < 4; ++r)
            Ob[(size_t)(lg * 4 + r) * EE + ns * 16 + lr] = (_Float16)(oacc[ns][r] * linv[r]);
}

// ---------------------------------------------------------------------------
// Kernel 2b: Wo f32 -> f16 (layout preserved = native B-fragment layout).
// ---------------------------------------------------------------------------
__global__ __launch_bounds__(256) void wconv_kernel(
    const float* __restrict__ W, _Float16* __restrict__ Wf)
{
    int i = (blockIdx.x * 256 + threadIdx.x) * 8;
    *(half8*)(Wf + i) = cvt8(W + i);
}

// ---------------------------------------------------------------------------
// Kernel 3 (r14): out = O @ Wo.T + bo, 64x128-tile MFMA GEMM.
// r12/r13 ran 256 blocks = 1 block/CU = 1 wave/SIMD: zero TLP, every
// global/LDS stall exposed. r14: 64x128 tiles -> 512 blocks = 2 blocks/CU
// = 2 waves/SIMD (LDS 54KB). XCD swizzle b = nb*64 + mb pins the *Of*
// m-tile to an XCD (XCD = b%8 = mb%8): per-XCD footprint = 8 m-tiles
// (1MB Of) + full Wf (2MB) < 4MB L2 -> Of fetched once from HBM (was 8x).
// HBM floor ~58MB ~= 9.5us.
// ---------------------------------------------------------------------------
__global__ __launch_bounds__(256, 2) void oproj_kernel(
    const _Float16* __restrict__ Of, const _Float16* __restrict__ Wf,
    const float* __restrict__ bo, float* __restrict__ out)
{
    int b = blockIdx.x;             // 0..511
    int mb = b & 63, nb = b >> 6;   // XCD = b%8 = mb%8 -> Of tile XCD-local
    int t = threadIdx.x, lane = t & 63, wid = t >> 6;
    int wm = wid >> 1, wn = wid & 1;
    int lr = lane & 15, lg = lane >> 4;
    int m0 = mb * 64, n0 = nb * 128;

    __shared__ __align__(16) _Float16 As[2][64][72];    // 2 x 9 KB
    __shared__ __align__(16) _Float16 Bs[2][128][72];   // 2 x 18 KB

    // staging maps: A: thread t covers row t>>2, 2 half8s at col (t&3)*16.
    //               B: thread t covers row t>>1, 4 half8s at col (t&1)*32.
    int arow = t >> 2, acol = (t & 3) * 16;
    int brow = t >> 1, bcol = (t & 1) * 32;
    const _Float16* Ag = Of + (size_t)(m0 + arow) * EE + acol;
    const _Float16* Bg = Wf + (size_t)(n0 + brow) * EE + bcol;

    floatx4 acc[2][4];
    #pragma unroll
    for (int sm = 0; sm < 2; ++sm)
        #pragma unroll
        for (int sn = 0; sn < 4; ++sn) acc[sm][sn] = (floatx4){0.f, 0.f, 0.f, 0.f};

    // ---- prologue: stage kb=0 into buffer 0
    #pragma unroll
    for (int j = 0; j < 2; ++j)
        *(half8*)(&As[0][arow][acol + j * 8]) = *(const half8*)(Ag + j * 8);
    #pragma unroll
    for (int j = 0; j < 4; ++j)
        *(half8*)(&Bs[0][brow][bcol + j * 8]) = *(const half8*)(Bg + j * 8);
    __syncthreads();

    int p = 0;
    for (int kb = 0; kb < EE; kb += 64, p ^= 1) {
        int kn = kb + 64;
        // ---- issue next chunk's global loads
        half8 sa[2], sb[4];
        if (kn < EE) {
            #pragma unroll
            for (int j = 0; j < 2; ++j) sa[j] = *(const half8*)(Ag + kn + j * 8);
            #pragma unroll
            for (int j = 0; j < 4; ++j) sb[j] = *(const half8*)(Bg + kn + j * 8);
        }
        // ---- compute on buffer p: 2 k-subchunks of 32
        #pragma unroll
        for (int kk = 0; kk < 2; ++kk) {
            half8 af[2], bf[4];
            #pragma unroll
            for (int s = 0; s < 2; ++s)
                af[s] = *(const half8*)(&As[p][wm * 32 + s * 16 + lr][kk * 32 + lg * 8]);
            #pragma unroll
            for (int s = 0; s < 4; ++s)
                bf[s] = *(const half8*)(&Bs[p][wn * 64 + s * 16 + lr][kk * 32 + lg * 8]);
            #pragma unroll
            for (int sm = 0; sm < 2; ++sm)
                #pragma unroll
                for (int sn = 0; sn < 4; ++sn)
                    acc[sm][sn] = __builtin_amdgcn_mfma_f32_16x16x32_f16(
                        af[sm], bf[sn], acc[sm][sn], 0, 0, 0);
        }
        // ---- write staged chunk into the other buffer
        if (kn < EE) {
            #pragma unroll
            for (int j = 0; j < 2; ++j)
                *(half8*)(&As[p ^ 1][arow][acol + j * 8]) = sa[j];
            #pragma unroll
            for (int j = 0; j < 4; ++j)
                *(half8*)(&Bs[p ^ 1][brow][bcol + j * 8]) = sb[j];
        }
        __syncthreads();
    }

    // ---- epilogue: C/D col = lr (n), row = lg*4+r (m)
    #pragma unroll
    for (int sn = 0; sn < 4; ++sn) {
        int nn = n0 + wn * 64 + sn * 16 + lr;
        float bn = bo[nn];
        #pragma unroll
        for (int sm = 0; sm < 2; ++sm) {
            #pragma unroll
            for (int r = 0; r < 4; ++r)
                out[(size_t)(m0 + wm * 32 + sm * 16 + lg * 4 + r) * EE + nn]
                    = acc[sm][sn][r] + bn;
        }
    }
}

// ---------------------------------------------------------------------------
extern "C" void kernel_launch(void* const* d_in, const int* in_sizes, int n_in,
                              void* d_out, int out_size, void* d_ws, size_t ws_size,
                              hipStream_t stream)
{
    const float* Q  = (const float*)d_in[0];
    const float* K  = (const float*)d_in[1];
    const float* V  = (const float*)d_in[2];
    const float* Wq = (const float*)d_in[3];
    const float* Wk = (const float*)d_in[4];
    const float* Wv = (const float*)d_in[5];
    const float* Wo = (const float*)d_in[6];
    const float* bo = (const float*)d_in[7];
    float* out = (float*)d_out;

    const size_t NSE = (size_t)NB * SS * EE;   // 4.19M elements
    _Float16* Qp = (_Float16*)d_ws;  // [nh][s][d] pre-scaled   8.4 MB
    _Float16* Kp = Qp + NSE;         // [nh][s][d]              8.4 MB
    _Float16* Vt = Kp + NSE;         // [nh][d][s] transposed   8.4 MB
    _Float16* Of = Vt + NSE;         // [n][s][e] f16           8.4 MB
    _Float16* Wf = Of + NSE;         // [1024][1024] f16        2.1 MB (~36 MB)

    proj_kernel<<<1024, 256, 0, stream>>>(Q, K, V, Wq, Wk, Wv, Qp, Kp, Vt);
    wconv_kernel<<<(EE * EE) / (256 * 8), 256, 0, stream>>>(Wo, Wf);
    attn_kernel<<<NHD * (SS / 64), 256, 0, stream>>>(Qp, Kp, Vt, Of);  // 1024
    oproj_kernel<<<512, 256, 0, stream>>>(Of, Wf, bo, out);
}

// Round 4
// 205.982 us; speedup vs baseline: 1.1695x; 1.0094x over previous
//
#include <hip/hip_runtime.h>
#include <hip/hip_bf16.h>

// Problem constants
#define NB 2
#define SS 2048
#define EE 1024
#define HH 16
#define DD 64
#define NHD (NB*HH)   // 32 (n,h) pairs
#define KT 64         // keys per flash tile

// fold softmax scale (1/sqrt(1024)) and log2(e) into Q' so P = exp2(S')
#define QSCALE 0.04508422002777998f

typedef _Float16 half8 __attribute__((ext_vector_type(8)));
typedef _Float16 half4 __attribute__((ext_vector_type(4)));
typedef float floatx4 __attribute__((ext_vector_type(4)));

__device__ __forceinline__ half8 cvt8(const float* p) {
    float4 x = *(const float4*)p;
    float4 y = *(const float4*)(p + 4);
    half8 h = { (_Float16)x.x, (_Float16)x.y, (_Float16)x.z, (_Float16)x.w,
                (_Float16)y.x, (_Float16)y.y, (_Float16)y.z, (_Float16)y.w };
    return h;
}

// packed f32x2 -> f16x2 (RTZ) returning raw u32
__device__ __forceinline__ unsigned int pkrtz_u32(float a, float b) {
    return __builtin_bit_cast(unsigned int, __builtin_amdgcn_cvt_pkrtz(a, b));
}

// XOR-swizzled index (in halves) for a [64-row][64-half] f16 LDS tile.
// 16B groups: group' = group ^ (row&7). Keeps b128 alignment, LDS = exact
// 40KB in attn -> 4 blocks/CU (r13-verified: occupancy 24.7->31.4).
__device__ __forceinline__ int swz64(int row, int colh) {
    return (row << 6) + ((((colh >> 3) ^ (row & 7)) << 3) | (colh & 7));
}

// ---------------------------------------------------------------------------
// Kernel 1 (r15): QKV projection via MFMA + absorbed Wo f32->f16 conversion
// (wconv deleted: each of 1024 blocks converts 1KB of Wo via 128 threads).
// Block = one (n,h) x 64 consecutive s; V transposed through LDS -> coalesced
// 32B Vt stores (r13, -17us verified).
// Outputs: Q' f16 [nh][s][d] pre-scaled, K' f16 [nh][s][d], V' f16 [nh][d][s],
//          Wf f16 [1024][1024].
// ---------------------------------------------------------------------------
__global__ __launch_bounds__(256) void proj_kernel(
    const float* __restrict__ Q, const float* __restrict__ K, const float* __restrict__ V,
    const float* __restrict__ Wq, const float* __restrict__ Wk, const float* __restrict__ Wv,
    const float* __restrict__ Wo,
    _Float16* __restrict__ Qp, _Float16* __restrict__ Kp, _Float16* __restrict__ Vt,
    _Float16* __restrict__ Wf)
{
    int t = threadIdx.x, lane = t & 63, wid = t >> 6;
    int lr = lane & 15, lg = lane >> 4;
    int b = blockIdx.x;             // 0..1023
    int nh = b >> 5, st = b & 31;   // head-pair, s-tile (64 rows)
    int n = nh >> 4, h = nh & 15;

    // absorbed wconv: 128 threads x 8 elems = 1KB of Wo per block
    if (t < 128) {
        int i = b * 1024 + t * 8;
        *(half8*)(Wf + i) = cvt8(Wo + i);
    }

    __shared__ __align__(16) _Float16 vt[DD][72];   // 9 KB transpose buffer

    // A-fragment rows: s = st*64 + wid*16 + lr  (m = lane&15)
    const size_t xoff = ((size_t)n * SS + st * 64 + wid * 16 + lr) * EE
                        + (size_t)h * DD + lg * 8;
    // C rows: s = st*64 + wid*16 + lg*4 + r
    const size_t qob = ((size_t)nh * SS + st * 64 + wid * 16 + lg * 4) * DD;

    const float* tens[3] = {Q, K, V};
    const float* wts[3]  = {Wq, Wk, Wv};

    #pragma unroll
    for (int x = 0; x < 3; ++x) {
        const float* Xr = tens[x] + xoff;
        half8 a0 = cvt8(Xr);
        half8 a1 = cvt8(Xr + 32);
        floatx4 acc[4];
        #pragma unroll
        for (int ns = 0; ns < 4; ++ns) {
            const float* Wr = wts[x] + (size_t)(ns * 16 + lr) * DD + lg * 8;
            half8 b0 = cvt8(Wr);
            half8 b1 = cvt8(Wr + 32);
            floatx4 c = (floatx4){0.f, 0.f, 0.f, 0.f};
            c = __builtin_amdgcn_mfma_f32_16x16x32_f16(a0, b0, c, 0, 0, 0);
            c = __builtin_amdgcn_mfma_f32_16x16x32_f16(a1, b1, c, 0, 0, 0);
            acc[ns] = c;
        }
        if (x == 0) {
            #pragma unroll
            for (int ns = 0; ns < 4; ++ns)
                #pragma unroll
                for (int r = 0; r < 4; ++r)
                    Qp[qob + (size_t)r * DD + ns * 16 + lr] = (_Float16)(acc[ns][r] * QSCALE);
        } else if (x == 1) {
            #pragma unroll
            for (int ns = 0; ns < 4; ++ns)
                #pragma unroll
                for (int r = 0; r < 4; ++r)
                    Kp[qob + (size_t)r * DD + ns * 16 + lr] = (_Float16)acc[ns][r];
        } else {
            // transpose in LDS: vt[d][s_local], d = ns*16+lr, s_local = wid*16+lg*4+r
            #pragma unroll
            for (int ns = 0; ns < 4; ++ns)
                #pragma unroll
                for (int r = 0; r < 4; ++r)
                    vt[ns * 16 + lr][wid * 16 + lg * 4 + r] = (_Float16)acc[ns][r];
        }
    }
    __syncthreads();
    // coalesced Vt store: thread t covers d = t>>2, 32 contiguous bytes of s.
    {
        int d = t >> 2, q4 = (t & 3) * 16;
        _Float16* dst = Vt + ((size_t)nh * DD + d) * SS + st * 64 + q4;
        *(half8*)dst       = *(const half8*)(&vt[d][q4]);
        *(half8*)(dst + 8) = *(const half8*)(&vt[d][q4 + 8]);
    }
}

// ---------------------------------------------------------------------------
// Kernel 2 (r15): flash MFMA attention, intra-iteration half-tile pipeline.
// r14 at 74.5us: MfmaUtil 22 / VALUBusy 60. The per-tile chain
// QK -> exp -> plds roundtrip -> PV is SERIAL within a wave; MFMA and VALU
// are separate pipes but nothing independent co-issues. r15 splits the
// 64-key tile into two 32-key halves and pipelines INSIDE the iteration:
//   QK(h0) -> [exp(h0) VALU || QK(h1) MFMA] -> [exp(h1) VALU || PV(h0) MFMA]
//   -> PV(h1)
// No cross-iteration register carry (VGPR peak kept <128 by reading vf
// after kf dies), no extra barriers, no new races (plds is wave-local).
// Fragment maps (m89/m120-verified): A/B[m][k]: m=lane&15, k=(lane>>4)*8+j.
// C/D[row][col]: col=lane&15, row=(lane>>4)*4+reg.
// vf[ns][j] = V[d=ns*16+lr][keys j*32+lg*8..]: j=0 -> keys 0..31 = half0.
// GRID: 1024 = 32 nh x 32 q-tiles. LDS 40KB -> 4 blocks/CU.
// ---------------------------------------------------------------------------
__global__ __launch_bounds__(256, 4) void attn_kernel(
    const _Float16* __restrict__ Qp, const _Float16* __restrict__ Kp,
    const _Float16* __restrict__ Vt, _Float16* __restrict__ Of)
{
    int b = blockIdx.x;                  // 0..1023
    int slot = b >> 3;                   // 0..127
    int nh = (b & 7) * 4 + (slot & 3);   // XCD swizzle: 4 heads per XCD in L2
    int qt = slot >> 2;                  // 0..31 (64-row q tile)
    int n = nh >> 4, h = nh & 15;
    int t = threadIdx.x;
    int lane = t & 63, wid = t >> 6;
    int lr = lane & 15;        // fragment row index / C col (= q here)
    int lg = lane >> 4;        // fragment k-group / C row-group

    __shared__ __align__(16) _Float16 kbuf[2][KT * DD];   // 2 x 8 KB, swizzled
    __shared__ __align__(16) _Float16 vbuf[2][DD * KT];   // 2 x 8 KB, swizzled
    __shared__ __align__(16) _Float16 plds[4][16 * 64];   // 8 KB, swizzled

    const _Float16* Qb = Qp + ((size_t)nh * SS + qt * 64 + wid * 16) * DD;
    const _Float16* Kb = Kp + (size_t)nh * SS * DD;
    const _Float16* Vb = Vt + (size_t)nh * DD * SS;

    // Q B-fragments, loaded once: n=q=lr, k=d = c*32 + lg*8 + j
    half8 qf0 = *(const half8*)(Qb + (size_t)lr * DD + lg * 8);
    half8 qf1 = *(const half8*)(Qb + (size_t)lr * DD + 32 + lg * 8);

    // ones B-fragment for the row-sum MFMA
    half8 ones = { (_Float16)1.f, (_Float16)1.f, (_Float16)1.f, (_Float16)1.f,
                   (_Float16)1.f, (_Float16)1.f, (_Float16)1.f, (_Float16)1.f };

    // staging map: slot s in [0,512): row = s>>3, colg = s&7 (8 half8s/row)
    int sr = t >> 3, sc = (t & 7) * 8;

    // ---- prologue: stage tile kb=0 into buffer 0
    {
        half8 k0 = *(const half8*)(Kb + (size_t)sr * DD + sc);
        half8 k1 = *(const half8*)(Kb + (size_t)(sr + 32) * DD + sc);
        half8 v0 = *(const half8*)(Vb + (size_t)sr * SS + sc);
        half8 v1 = *(const half8*)(Vb + (size_t)(sr + 32) * SS + sc);
        *(half8*)(&kbuf[0][swz64(sr, sc)]) = k0;
        *(half8*)(&kbuf[0][swz64(sr + 32, sc)]) = k1;
        *(half8*)(&vbuf[0][swz64(sr, sc)]) = v0;
        *(half8*)(&vbuf[0][swz64(sr + 32, sc)]) = v1;
    }
    __syncthreads();

    floatx4 oacc[4];
    #pragma unroll
    for (int ns = 0; ns < 4; ++ns) oacc[ns] = (floatx4){0.f, 0.f, 0.f, 0.f};
    floatx4 sacc = (floatx4){0.f, 0.f, 0.f, 0.f};   // row sums via ones-MFMA

    int p = 0;
    for (int kb = 0; kb < SS; kb += KT, p ^= 1) {
        // ---- issue global loads for tile t+1 (wrap at end: dummy, unused)
        int kn = (kb + KT) & (SS - 1);
        half8 sk0 = *(const half8*)(Kb + (size_t)(kn + sr) * DD + sc);
        half8 sk1 = *(const half8*)(Kb + (size_t)(kn + sr + 32) * DD + sc);
        half8 sv0 = *(const half8*)(Vb + (size_t)sr * SS + kn + sc);
        half8 sv1 = *(const half8*)(Vb + (size_t)(sr + 32) * SS + kn + sc);

        // ---- K A-fragments from LDS (m=key rows): kbuf[key][d]
        half8 kf[4][2];
        #pragma unroll
        for (int ns = 0; ns < 4; ++ns) {
            kf[ns][0] = *(const half8*)(&kbuf[p][swz64(ns * 16 + lr, lg * 8)]);
            kf[ns][1] = *(const half8*)(&kbuf[p][swz64(ns * 16 + lr, 32 + lg * 8)]);
        }
        // ---- QK half0 (keys 0..31): S^T = K Q^T, D[key][q]
        floatx4 s0 = (floatx4){0.f, 0.f, 0.f, 0.f};
        floatx4 s1 = (floatx4){0.f, 0.f, 0.f, 0.f};
        s0 = __builtin_amdgcn_mfma_f32_16x16x32_f16(kf[0][0], qf0, s0, 0, 0, 0);
        s0 = __builtin_amdgcn_mfma_f32_16x16x32_f16(kf[0][1], qf1, s0, 0, 0, 0);
        s1 = __builtin_amdgcn_mfma_f32_16x16x32_f16(kf[1][0], qf0, s1, 0, 0, 0);
        s1 = __builtin_amdgcn_mfma_f32_16x16x32_f16(kf[1][1], qf1, s1, 0, 0, 0);

        // ---- exp half0 (VALU) — co-issues with QK half1 (MFMA) below
        {
            float p0 = exp2f(fminf(s0[0], 50.f)), p1 = exp2f(fminf(s0[1], 50.f));
            float p2 = exp2f(fminf(s0[2], 50.f)), p3 = exp2f(fminf(s0[3], 50.f));
            uint2 pr; pr.x = pkrtz_u32(p0, p1); pr.y = pkrtz_u32(p2, p3);
            *(uint2*)(&plds[wid][swz64(lr, 0 * 16 + lg * 4)]) = pr;
        }
        {
            float p0 = exp2f(fminf(s1[0], 50.f)), p1 = exp2f(fminf(s1[1], 50.f));
            float p2 = exp2f(fminf(s1[2], 50.f)), p3 = exp2f(fminf(s1[3], 50.f));
            uint2 pr; pr.x = pkrtz_u32(p0, p1); pr.y = pkrtz_u32(p2, p3);
            *(uint2*)(&plds[wid][swz64(lr, 1 * 16 + lg * 4)]) = pr;
        }

        // ---- QK half1 (keys 32..63)
        floatx4 s2 = (floatx4){0.f, 0.f, 0.f, 0.f};
        floatx4 s3 = (floatx4){0.f, 0.f, 0.f, 0.f};
        s2 = __builtin_amdgcn_mfma_f32_16x16x32_f16(kf[2][0], qf0, s2, 0, 0, 0);
        s2 = __builtin_amdgcn_mfma_f32_16x16x32_f16(kf[2][1], qf1, s2, 0, 0, 0);
        s3 = __builtin_amdgcn_mfma_f32_16x16x32_f16(kf[3][0], qf0, s3, 0, 0, 0);
        s3 = __builtin_amdgcn_mfma_f32_16x16x32_f16(kf[3][1], qf1, s3, 0, 0, 0);

        // ---- V B-fragments from LDS (after kf dies: VGPR peak < 128)
        half8 vf[4][2];
        #pragma unroll
        for (int ns = 0; ns < 4; ++ns) {
            vf[ns][0] = *(const half8*)(&vbuf[p][swz64(ns * 16 + lr, lg * 8)]);
            vf[ns][1] = *(const half8*)(&vbuf[p][swz64(ns * 16 + lr, 32 + lg * 8)]);
        }

        // ---- drain half0 P stores; read pf0
        asm volatile("s_waitcnt lgkmcnt(0)" ::: "memory");
        half8 pf0 = *(const half8*)(&plds[wid][swz64(lr, lg * 8)]);

        // ---- exp half1 (VALU) — co-issues with PV half0 (MFMA) below
        {
            float p0 = exp2f(fminf(s2[0], 50.f)), p1 = exp2f(fminf(s2[1], 50.f));
            float p2 = exp2f(fminf(s2[2], 50.f)), p3 = exp2f(fminf(s2[3], 50.f));
            uint2 pr; pr.x = pkrtz_u32(p0, p1); pr.y = pkrtz_u32(p2, p3);
            *(uint2*)(&plds[wid][swz64(lr, 2 * 16 + lg * 4)]) = pr;
        }
        {
            float p0 = exp2f(fminf(s3[0], 50.f)), p1 = exp2f(fminf(s3[1], 50.f));
            float p2 = exp2f(fminf(s3[2], 50.f)), p3 = exp2f(fminf(s3[3], 50.f));
            uint2 pr; pr.x = pkrtz_u32(p0, p1); pr.y = pkrtz_u32(p2, p3);
            *(uint2*)(&plds[wid][swz64(lr, 3 * 16 + lg * 4)]) = pr;
        }

        // ---- PV half0 + row-sum (keys 0..31)
        #pragma unroll
        for (int ns = 0; ns < 4; ++ns)
            oacc[ns] = __builtin_amdgcn_mfma_f32_16x16x32_f16(pf0, vf[ns][0], oacc[ns], 0, 0, 0);
        sacc = __builtin_amdgcn_mfma_f32_16x16x32_f16(pf0, ones, sacc, 0, 0, 0);

        // ---- drain half1 P stores; read pf1
        asm volatile("s_waitcnt lgkmcnt(0)" ::: "memory");
        half8 pf1 = *(const half8*)(&plds[wid][swz64(lr, 32 + lg * 8)]);

        // ---- PV half1 + row-sum (keys 32..63)
        #pragma unroll
        for (int ns = 0; ns < 4; ++ns)
            oacc[ns] = __builtin_amdgcn_mfma_f32_16x16x32_f16(pf1, vf[ns][1], oacc[ns], 0, 0, 0);
        sacc = __builtin_amdgcn_mfma_f32_16x16x32_f16(pf1, ones, sacc, 0, 0, 0);

        // ---- write staged tile t+1 into the other buffer, then barrier
        *(half8*)(&kbuf[p ^ 1][swz64(sr, sc)]) = sk0;
        *(half8*)(&kbuf[p ^ 1][swz64(sr + 32, sc)]) = sk1;
        *(half8*)(&vbuf[p ^ 1][swz64(sr, sc)]) = sv0;
        *(half8*)(&vbuf[p ^ 1][swz64(sr + 32, sc)]) = sv1;
        __syncthreads();
    }

    // ---- normalization: sacc row layout (lg*4+r) matches oacc rows exactly.
    float linv[4];
    #pragma unroll
    for (int r = 0; r < 4; ++r)
        linv[r] = 1.f / sacc[r];

    // ---- write O (f16, [n][s][e]): row q = lg*4+r, col = h*64 + ns*16 + lr
    _Float16* Ob = Of + ((size_t)n * SS + qt * 64 + wid * 16) * EE + h * DD;
    #pragma unroll
    for (int ns = 0; ns < 4; ++ns)
        #pragma unroll
        for (int r = 0; r < 4; ++r)
            Ob[(size_t)(lg * 4 + r) * EE + ns * 16 + lr] = (_Float16)(oacc[ns][r] * linv[r]);
}

// ---------------------------------------------------------------------------
// Kernel 3 (r14, unchanged): out = O @ Wo.T + bo, 64x128-tile MFMA GEMM.
// 512 blocks = 2 blocks/CU; XCD swizzle pins Of m-tile per XCD L2.
// ---------------------------------------------------------------------------
__global__ __launch_bounds__(256, 2) void oproj_kernel(
    const _Float16* __restrict__ Of, const _Float16* __restrict__ Wf,
    const float* __restrict__ bo, float* __restrict__ out)
{
    int b = blockIdx.x;             // 0..511
    int mb = b & 63, nb = b >> 6;   // XCD = b%8 = mb%8 -> Of tile XCD-local
    int t = threadIdx.x, lane = t & 63, wid = t >> 6;
    int wm = wid >> 1, wn = wid & 1;
    int lr = lane & 15, lg = lane >> 4;
    int m0 = mb * 64, n0 = nb * 128;

    __shared__ __align__(16) _Float16 As[2][64][72];    // 2 x 9 KB
    __shared__ __align__(16) _Float16 Bs[2][128][72];   // 2 x 18 KB

    // staging maps: A: thread t covers row t>>2, 2 half8s at col (t&3)*16.
    //               B: thread t covers row t>>1, 4 half8s at col (t&1)*32.
    int arow = t >> 2, acol = (t & 3) * 16;
    int brow = t >> 1, bcol = (t & 1) * 32;
    const _Float16* Ag = Of + (size_t)(m0 + arow) * EE + acol;
    const _Float16* Bg = Wf + (size_t)(n0 + brow) * EE + bcol;

    floatx4 acc[2][4];
    #pragma unroll
    for (int sm = 0; sm < 2; ++sm)
        #pragma unroll
        for (int sn = 0; sn < 4; ++sn) acc[sm][sn] = (floatx4){0.f, 0.f, 0.f, 0.f};

    // ---- prologue: stage kb=0 into buffer 0
    #pragma unroll
    for (int j = 0; j < 2; ++j)
        *(half8*)(&As[0][arow][acol + j * 8]) = *(const half8*)(Ag + j * 8);
    #pragma unroll
    for (int j = 0; j < 4; ++j)
        *(half8*)(&Bs[0][brow][bcol + j * 8]) = *(const half8*)(Bg + j * 8);
    __syncthreads();

    int p = 0;
    for (int kb = 0; kb < EE; kb += 64, p ^= 1) {
        int kn = kb + 64;
        // ---- issue next chunk's global loads
        half8 sa[2], sb[4];
        if (kn < EE) {
            #pragma unroll
            for (int j = 0; j < 2; ++j) sa[j] = *(const half8*)(Ag + kn + j * 8);
            #pragma unroll
            for (int j = 0; j < 4; ++j) sb[j] = *(const half8*)(Bg + kn + j * 8);
        }
        // ---- compute on buffer p: 2 k-subchunks of 32
        #pragma unroll
        for (int kk = 0; kk < 2; ++kk) {
            half8 af[2], bf[4];
            #pragma unroll
            for (int s = 0; s < 2; ++s)
                af[s] = *(const half8*)(&As[p][wm * 32 + s * 16 + lr][kk * 32 + lg * 8]);
            #pragma unroll
            for (int s = 0; s < 4; ++s)
                bf[s] = *(const half8*)(&Bs[p][wn * 64 + s * 16 + lr][kk * 32 + lg * 8]);
            #pragma unroll
            for (int sm = 0; sm < 2; ++sm)
                #pragma unroll
                for (int sn = 0; sn < 4; ++sn)
                    acc[sm][sn] = __builtin_amdgcn_mfma_f32_16x16x32_f16(
                        af[sm], bf[sn], acc[sm][sn], 0, 0, 0);
        }
        // ---- write staged chunk into the other buffer
        if (kn < EE) {
            #pragma unroll
            for (int j = 0; j < 2; ++j)
                *(half8*)(&As[p ^ 1][arow][acol + j * 8]) = sa[j];
            #pragma unroll
            for (int j = 0; j < 4; ++j)
                *(half8*)(&Bs[p ^ 1][brow][bcol + j * 8]) = sb[j];
        }
        __syncthreads();
    }

    // ---- epilogue: C/D col = lr (n), row = lg*4+r (m)
    #pragma unroll
    for (int sn = 0; sn < 4; ++sn) {
        int nn = n0 + wn * 64 + sn * 16 + lr;
        float bn = bo[nn];
        #pragma unroll
        for (int sm = 0; sm < 2; ++sm) {
            #pragma unroll
            for (int r = 0; r < 4; ++r)
                out[(size_t)(m0 + wm * 32 + sm * 16 + lg * 4 + r) * EE + nn]
                    = acc[sm][sn][r] + bn;
        }
    }
}

// ---------------------------------------------------------------------------
extern "C" void kernel_launch(void* const* d_in, const int* in_sizes, int n_in,
                              void* d_out, int out_size, void* d_ws, size_t ws_size,
                              hipStream_t stream)
{
    const float* Q  = (const float*)d_in[0];
    const float* K  = (const float*)d_in[1];
    const float* V  = (const float*)d_in[2];
    const float* Wq = (const float*)d_in[3];
    const float* Wk = (const float*)d_in[4];
    const float* Wv = (const float*)d_in[5];
    const float* Wo = (const float*)d_in[6];
    const float* bo = (const float*)d_in[7];
    float* out = (float*)d_out;

    const size_t NSE = (size_t)NB * SS * EE;   // 4.19M elements
    _Float16* Qp = (_Float16*)d_ws;  // [nh][s][d] pre-scaled   8.4 MB
    _Float16* Kp = Qp + NSE;         // [nh][s][d]              8.4 MB
    _Float16* Vt = Kp + NSE;         // [nh][d][s] transposed   8.4 MB
    _Float16* Of = Vt + NSE;         // [n][s][e] f16           8.4 MB
    _Float16* Wf = Of + NSE;         // [1024][1024] f16        2.1 MB (~36 MB)

    proj_kernel<<<1024, 256, 0, stream>>>(Q, K, V, Wq, Wk, Wv, Wo, Qp, Kp, Vt, Wf);
    attn_kernel<<<NHD * (SS / 64), 256, 0, stream>>>(Qp, Kp, Vt, Of);  // 1024
    oproj_kernel<<<512, 256, 0, stream>>>(Of, Wf, bo, out);
}

// Round 5
// 203.471 us; speedup vs baseline: 1.1839x; 1.0123x over previous
//
#include <hip/hip_runtime.h>
#include <hip/hip_bf16.h>

// Problem constants
#define NB 2
#define SS 2048
#define EE 1024
#define HH 16
#define DD 64
#define NHD (NB*HH)   // 32 (n,h) pairs
#define KT 64         // keys per flash tile

// fold softmax scale (1/sqrt(1024)) and log2(e) into Q' so P = exp2(S')
#define QSCALE 0.04508422002777998f

typedef _Float16 half8 __attribute__((ext_vector_type(8)));
typedef float floatx4 __attribute__((ext_vector_type(4)));
typedef float floatx16 __attribute__((ext_vector_type(16)));

__device__ __forceinline__ half8 cvt8(const float* p) {
    float4 x = *(const float4*)p;
    float4 y = *(const float4*)(p + 4);
    half8 h = { (_Float16)x.x, (_Float16)x.y, (_Float16)x.z, (_Float16)x.w,
                (_Float16)y.x, (_Float16)y.y, (_Float16)y.z, (_Float16)y.w };
    return h;
}

// packed f32x2 -> f16x2 (RTZ) returning raw u32
__device__ __forceinline__ unsigned int pkrtz_u32(float a, float b) {
    return __builtin_bit_cast(unsigned int, __builtin_amdgcn_cvt_pkrtz(a, b));
}

// XOR-swizzled index (in halves) for a [64-row][64-half] f16 LDS tile.
// 16B groups: group' = group ^ (row&7). Keeps b128 alignment (r13-verified).
__device__ __forceinline__ int swz64(int row, int colh) {
    return (row << 6) + ((((colh >> 3) ^ (row & 7)) << 3) | (colh & 7));
}

// ---------------------------------------------------------------------------
// Kernel 1 (r15, unchanged): QKV projection via MFMA + absorbed Wo f32->f16.
// Outputs: Q' f16 [nh][s][d] pre-scaled, K' f16 [nh][s][d], V' f16 [nh][d][s],
//          Wf f16 [1024][1024].
// ---------------------------------------------------------------------------
__global__ __launch_bounds__(256) void proj_kernel(
    const float* __restrict__ Q, const float* __restrict__ K, const float* __restrict__ V,
    const float* __restrict__ Wq, const float* __restrict__ Wk, const float* __restrict__ Wv,
    const float* __restrict__ Wo,
    _Float16* __restrict__ Qp, _Float16* __restrict__ Kp, _Float16* __restrict__ Vt,
    _Float16* __restrict__ Wf)
{
    int t = threadIdx.x, lane = t & 63, wid = t >> 6;
    int lr = lane & 15, lg = lane >> 4;
    int b = blockIdx.x;             // 0..1023
    int nh = b >> 5, st = b & 31;   // head-pair, s-tile (64 rows)
    int n = nh >> 4, h = nh & 15;

    // absorbed wconv: 128 threads x 8 elems = 1KB of Wo per block
    if (t < 128) {
        int i = b * 1024 + t * 8;
        *(half8*)(Wf + i) = cvt8(Wo + i);
    }

    __shared__ __align__(16) _Float16 vt[DD][72];   // 9 KB transpose buffer

    // A-fragment rows: s = st*64 + wid*16 + lr  (m = lane&15)
    const size_t xoff = ((size_t)n * SS + st * 64 + wid * 16 + lr) * EE
                        + (size_t)h * DD + lg * 8;
    // C rows: s = st*64 + wid*16 + lg*4 + r
    const size_t qob = ((size_t)nh * SS + st * 64 + wid * 16 + lg * 4) * DD;

    const float* tens[3] = {Q, K, V};
    const float* wts[3]  = {Wq, Wk, Wv};

    #pragma unroll
    for (int x = 0; x < 3; ++x) {
        const float* Xr = tens[x] + xoff;
        half8 a0 = cvt8(Xr);
        half8 a1 = cvt8(Xr + 32);
        floatx4 acc[4];
        #pragma unroll
        for (int ns = 0; ns < 4; ++ns) {
            const float* Wr = wts[x] + (size_t)(ns * 16 + lr) * DD + lg * 8;
            half8 b0 = cvt8(Wr);
            half8 b1 = cvt8(Wr + 32);
            floatx4 c = (floatx4){0.f, 0.f, 0.f, 0.f};
            c = __builtin_amdgcn_mfma_f32_16x16x32_f16(a0, b0, c, 0, 0, 0);
            c = __builtin_amdgcn_mfma_f32_16x16x32_f16(a1, b1, c, 0, 0, 0);
            acc[ns] = c;
        }
        if (x == 0) {
            #pragma unroll
            for (int ns = 0; ns < 4; ++ns)
                #pragma unroll
                for (int r = 0; r < 4; ++r)
                    Qp[qob + (size_t)r * DD + ns * 16 + lr] = (_Float16)(acc[ns][r] * QSCALE);
        } else if (x == 1) {
            #pragma unroll
            for (int ns = 0; ns < 4; ++ns)
                #pragma unroll
                for (int r = 0; r < 4; ++r)
                    Kp[qob + (size_t)r * DD + ns * 16 + lr] = (_Float16)acc[ns][r];
        } else {
            // transpose in LDS: vt[d][s_local], d = ns*16+lr, s_local = wid*16+lg*4+r
            #pragma unroll
            for (int ns = 0; ns < 4; ++ns)
                #pragma unroll
                for (int r = 0; r < 4; ++r)
                    vt[ns * 16 + lr][wid * 16 + lg * 4 + r] = (_Float16)acc[ns][r];
        }
    }
    __syncthreads();
    // coalesced Vt store: thread t covers d = t>>2, 32 contiguous bytes of s.
    {
        int d = t >> 2, q4 = (t & 3) * 16;
        _Float16* dst = Vt + ((size_t)nh * DD + d) * SS + st * 64 + q4;
        *(half8*)dst       = *(const half8*)(&vt[d][q4]);
        *(half8*)(dst + 8) = *(const half8*)(&vt[d][q4 + 8]);
    }
}

// ---------------------------------------------------------------------------
// Kernel 2 (r16): flash MFMA attention, 32x32 MFMA + in-register P.
// r13-r15 post-mortem: attn is LDS-BANDWIDTH-bound, not VALU-bound.
// r15 traffic: 24 KB LDS per wave-iter for 16 q-rows = 3.15 GB total
// (~70us at realistic LDS BW = the measured 74.7us). r16 cuts bytes/work:
//  (a) 32 q-rows/wave via mfma_f32_32x32x16_f16 (4-wave block = 128 q):
//      K/V fragment reads (16 KB/wave/iter) amortize over 2x q-rows.
//  (b) plds DELETED: P redistribution in-register. S^T=K Q^T in 32x32
//      layout puts P[q=lane&31][keys 8g+4h..+3] in lane (h=lane>>5);
//      after cvt_pkrtz pairing, 2 v_permlane32_swap_b32 per 16-key chunk
//      yield the PV A-fragment for both lane halves. No LDS round-trip,
//      no lgkmcnt drains. Row-sum ones-MFMA consumes the same pf regs
//      (denominator common-mode with PV, as r14).
// Traffic: (kf 8 + vf 8 + staging 4) KB per wave-iter for 32 q = 1.31 GB.
// LDS 32 KB/block; grid 512 = 32 nh x 16 q-tiles; 2 blocks/CU, 8 waves/CU.
// 32x32 frag maps (extrapolated from verified 16x16): A/B[m][k]:
// m=lane&31, k=(lane>>5)*8+j. C/D: col=lane&31, row=(r&3)+8*(r>>2)+4*(lane>>5).
// ---------------------------------------------------------------------------
__global__ __launch_bounds__(256, 2) void attn_kernel(
    const _Float16* __restrict__ Qp, const _Float16* __restrict__ Kp,
    const _Float16* __restrict__ Vt, _Float16* __restrict__ Of)
{
    int b = blockIdx.x;                  // 0..511
    int slot = b >> 3;                   // 0..63
    int nh = (b & 7) * 4 + (slot & 3);   // XCD swizzle: 4 heads per XCD in L2
    int qt = slot >> 2;                  // 0..15 (128-row q tile)
    int n = nh >> 4, h = nh & 15;
    int t = threadIdx.x;
    int lane = t & 63, wid = t >> 6;
    int l31 = lane & 31, h5 = lane >> 5;

    __shared__ __align__(16) _Float16 kbuf[2][KT * DD];   // 2 x 8 KB, swizzled
    __shared__ __align__(16) _Float16 vbuf[2][DD * KT];   // 2 x 8 KB, swizzled

    const _Float16* Kb = Kp + (size_t)nh * SS * DD;
    const _Float16* Vb = Vt + (size_t)nh * DD * SS;

    // Q B-fragments, loaded once: n=q=l31 (row), k=d = c*16 + h5*8 + j
    const _Float16* Qb = Qp + ((size_t)nh * SS + qt * 128 + wid * 32 + l31) * DD;
    half8 qf[4];
    #pragma unroll
    for (int c = 0; c < 4; ++c)
        qf[c] = *(const half8*)(Qb + c * 16 + h5 * 8);

    // ones B-fragment for the row-sum MFMA
    half8 ones = { (_Float16)1.f, (_Float16)1.f, (_Float16)1.f, (_Float16)1.f,
                   (_Float16)1.f, (_Float16)1.f, (_Float16)1.f, (_Float16)1.f };

    // staging map: slot s in [0,512): row = s>>3, colg = s&7 (8 half8s/row)
    int sr = t >> 3, sc = (t & 7) * 8;

    // ---- prologue: stage tile kb=0 into buffer 0
    {
        half8 k0 = *(const half8*)(Kb + (size_t)sr * DD + sc);
        half8 k1 = *(const half8*)(Kb + (size_t)(sr + 32) * DD + sc);
        half8 v0 = *(const half8*)(Vb + (size_t)sr * SS + sc);
        half8 v1 = *(const half8*)(Vb + (size_t)(sr + 32) * SS + sc);
        *(half8*)(&kbuf[0][swz64(sr, sc)]) = k0;
        *(half8*)(&kbuf[0][swz64(sr + 32, sc)]) = k1;
        *(half8*)(&vbuf[0][swz64(sr, sc)]) = v0;
        *(half8*)(&vbuf[0][swz64(sr + 32, sc)]) = v1;
    }
    __syncthreads();

    floatx16 oacc0 = {}, oacc1 = {};   // O for d-tiles 0,1
    floatx16 sacc  = {};               // row sums via ones-MFMA

    int p = 0;
    for (int kb = 0; kb < SS; kb += KT, p ^= 1) {
        // ---- issue global loads for tile t+1 (wrap at end: dummy, unused)
        int kn = (kb + KT) & (SS - 1);
        half8 sk0 = *(const half8*)(Kb + (size_t)(kn + sr) * DD + sc);
        half8 sk1 = *(const half8*)(Kb + (size_t)(kn + sr + 32) * DD + sc);
        half8 sv0 = *(const half8*)(Vb + (size_t)sr * SS + kn + sc);
        half8 sv1 = *(const half8*)(Vb + (size_t)(sr + 32) * SS + kn + sc);

        // ---- S^T = K Q^T for both 32-key subtiles: D[key][q]
        floatx16 s0 = {}, s1 = {};
        #pragma unroll
        for (int c = 0; c < 4; ++c) {
            half8 kf0 = *(const half8*)(&kbuf[p][swz64(l31,      c * 16 + h5 * 8)]);
            half8 kf1 = *(const half8*)(&kbuf[p][swz64(32 + l31, c * 16 + h5 * 8)]);
            s0 = __builtin_amdgcn_mfma_f32_32x32x16_f16(kf0, qf[c], s0, 0, 0, 0);
            s1 = __builtin_amdgcn_mfma_f32_32x32x16_f16(kf1, qf[c], s1, 0, 0, 0);
        }

        // ---- exp2 + pack + permlane redistribution -> PV A-fragments.
        // Lane (q=l31, h=h5) reg r of s: key = (r&3) + 8*(r>>2) + 4*h5.
        // After pk: w[2g],w[2g+1] = keys [8g+4h5 .. 8g+4h5+3].
        // swap(w[2g0], w[2g1]) (g0=2kc,g1=2kc+1) gives word0 in arg0,
        // word2 in arg1 of the chunk-kc A-frag; odd pair gives words 1,3.
        half8 pf[4];
        #pragma unroll
        for (int kt2 = 0; kt2 < 2; ++kt2) {
            const floatx16& sv = kt2 ? s1 : s0;
            unsigned int w0, w1, w2, w3, w4, w5, w6, w7;
            {
                float e0 = exp2f(fminf(sv[0], 50.f)), e1 = exp2f(fminf(sv[1], 50.f));
                float e2 = exp2f(fminf(sv[2], 50.f)), e3 = exp2f(fminf(sv[3], 50.f));
                w0 = pkrtz_u32(e0, e1); w1 = pkrtz_u32(e2, e3);
            }
            {
                float e0 = exp2f(fminf(sv[4], 50.f)), e1 = exp2f(fminf(sv[5], 50.f));
                float e2 = exp2f(fminf(sv[6], 50.f)), e3 = exp2f(fminf(sv[7], 50.f));
                w2 = pkrtz_u32(e0, e1); w3 = pkrtz_u32(e2, e3);
            }
            {
                float e0 = exp2f(fminf(sv[8], 50.f)), e1 = exp2f(fminf(sv[9], 50.f));
                float e2 = exp2f(fminf(sv[10], 50.f)), e3 = exp2f(fminf(sv[11], 50.f));
                w4 = pkrtz_u32(e0, e1); w5 = pkrtz_u32(e2, e3);
            }
            {
                float e0 = exp2f(fminf(sv[12], 50.f)), e1 = exp2f(fminf(sv[13], 50.f));
                float e2 = exp2f(fminf(sv[14], 50.f)), e3 = exp2f(fminf(sv[15], 50.f));
                w6 = pkrtz_u32(e0, e1); w7 = pkrtz_u32(e2, e3);
            }
            asm("v_permlane32_swap_b32 %0, %1" : "+v"(w0), "+v"(w2));
            asm("v_permlane32_swap_b32 %0, %1" : "+v"(w1), "+v"(w3));
            asm("v_permlane32_swap_b32 %0, %1" : "+v"(w4), "+v"(w6));
            asm("v_permlane32_swap_b32 %0, %1" : "+v"(w5), "+v"(w7));
            uint4 ua = {w0, w1, w2, w3};
            uint4 ub = {w4, w5, w6, w7};
            pf[kt2 * 2 + 0] = __builtin_bit_cast(half8, ua);
            pf[kt2 * 2 + 1] = __builtin_bit_cast(half8, ub);
        }

        // ---- O += P V ; row-sum += P * ones. B = V[key][d] from vbuf[d][key].
        #pragma unroll
        for (int c = 0; c < 4; ++c) {
            half8 vf0 = *(const half8*)(&vbuf[p][swz64(l31,      c * 16 + h5 * 8)]);
            half8 vf1 = *(const half8*)(&vbuf[p][swz64(32 + l31, c * 16 + h5 * 8)]);
            oacc0 = __builtin_amdgcn_mfma_f32_32x32x16_f16(pf[c], vf0, oacc0, 0, 0, 0);
            oacc1 = __builtin_amdgcn_mfma_f32_32x32x16_f16(pf[c], vf1, oacc1, 0, 0, 0);
            sacc  = __builtin_amdgcn_mfma_f32_32x32x16_f16(pf[c], ones, sacc, 0, 0, 0);
        }

        // ---- write staged tile t+1 into the other buffer, then barrier
        *(half8*)(&kbuf[p ^ 1][swz64(sr, sc)]) = sk0;
        *(half8*)(&kbuf[p ^ 1][swz64(sr + 32, sc)]) = sk1;
        *(half8*)(&vbuf[p ^ 1][swz64(sr, sc)]) = sv0;
        *(half8*)(&vbuf[p ^ 1][swz64(sr + 32, sc)]) = sv1;
        __syncthreads();
    }

    // ---- normalize and store. Reg r: q_local = (r&3)+8*(r>>2)+4*h5,
    // d = dt*32 + l31. sacc reg r matches oacc reg r's q row exactly.
    _Float16* Ob = Of + ((size_t)n * SS + qt * 128 + wid * 32) * EE + h * DD;
    #pragma unroll
    for (int r = 0; r < 16; ++r) {
        float linv = 1.f / sacc[r];
        int qrow = (r & 3) + 8 * (r >> 2) + 4 * h5;
        Ob[(size_t)qrow * EE + l31]      = (_Float16)(oacc0[r] * linv);
        Ob[(size_t)qrow * EE + 32 + l31] = (_Float16)(oacc1[r] * linv);
    }
}

// ---------------------------------------------------------------------------
// Kernel 3 (r14, unchanged): out = O @ Wo.T + bo, 64x128-tile MFMA GEMM.
// 512 blocks = 2 blocks/CU; XCD swizzle pins Of m-tile per XCD L2.
// ---------------------------------------------------------------------------
__global__ __launch_bounds__(256, 2) void oproj_kernel(
    const _Float16* __restrict__ Of, const _Float16* __restrict__ Wf,
    const float* __restrict__ bo, float* __restrict__ out)
{
    int b = blockIdx.x;             // 0..511
    int mb = b & 63, nb = b >> 6;   // XCD = b%8 = mb%8 -> Of tile XCD-local
    int t = threadIdx.x, lane = t & 63, wid = t >> 6;
    int wm = wid >> 1, wn = wid & 1;
    int lr = lane & 15, lg = lane >> 4;
    int m0 = mb * 64, n0 = nb * 128;

    __shared__ __align__(16) _Float16 As[2][64][72];    // 2 x 9 KB
    __shared__ __align__(16) _Float16 Bs[2][128][72];   // 2 x 18 KB

    // staging maps: A: thread t covers row t>>2, 2 half8s at col (t&3)*16.
    //               B: thread t covers row t>>1, 4 half8s at col (t&1)*32.
    int arow = t >> 2, acol = (t & 3) * 16;
    int brow = t >> 1, bcol = (t & 1) * 32;
    const _Float16* Ag = Of + (size_t)(m0 + arow) * EE + acol;
    const _Float16* Bg = Wf + (size_t)(n0 + brow) * EE + bcol;

    floatx4 acc[2][4];
    #pragma unroll
    for (int sm = 0; sm < 2; ++sm)
        #pragma unroll
        for (int sn = 0; sn < 4; ++sn) acc[sm][sn] = (floatx4){0.f, 0.f, 0.f, 0.f};

    // ---- prologue: stage kb=0 into buffer 0
    #pragma unroll
    for (int j = 0; j < 2; ++j)
        *(half8*)(&As[0][arow][acol + j * 8]) = *(const half8*)(Ag + j * 8);
    #pragma unroll
    for (int j = 0; j < 4; ++j)
        *(half8*)(&Bs[0][brow][bcol + j * 8]) = *(const half8*)(Bg + j * 8);
    __syncthreads();

    int p = 0;
    for (int kb = 0; kb < EE; kb += 64, p ^= 1) {
        int kn = kb + 64;
        // ---- issue next chunk's global loads
        half8 sa[2], sb[4];
        if (kn < EE) {
            #pragma unroll
            for (int j = 0; j < 2; ++j) sa[j] = *(const half8*)(Ag + kn + j * 8);
            #pragma unroll
            for (int j = 0; j < 4; ++j) sb[j] = *(const half8*)(Bg + kn + j * 8);
        }
        // ---- compute on buffer p: 2 k-subchunks of 32
        #pragma unroll
        for (int kk = 0; kk < 2; ++kk) {
            half8 af[2], bf[4];
            #pragma unroll
            for (int s = 0; s < 2; ++s)
                af[s] = *(const half8*)(&As[p][wm * 32 + s * 16 + lr][kk * 32 + lg * 8]);
            #pragma unroll
            for (int s = 0; s < 4; ++s)
                bf[s] = *(const half8*)(&Bs[p][wn * 64 + s * 16 + lr][kk * 32 + lg * 8]);
            #pragma unroll
            for (int sm = 0; sm < 2; ++sm)
                #pragma unroll
                for (int sn = 0; sn < 4; ++sn)
                    acc[sm][sn] = __builtin_amdgcn_mfma_f32_16x16x32_f16(
                        af[sm], bf[sn], acc[sm][sn], 0, 0, 0);
        }
        // ---- write staged chunk into the other buffer
        if (kn < EE) {
            #pragma unroll
            for (int j = 0; j < 2; ++j)
                *(half8*)(&As[p ^ 1][arow][acol + j * 8]) = sa[j];
            #pragma unroll
            for (int j = 0; j < 4; ++j)
                *(half8*)(&Bs[p ^ 1][brow][bcol + j * 8]) = sb[j];
        }
        __syncthreads();
    }

    // ---- epilogue: C/D col = lr (n), row = lg*4+r (m)
    #pragma unroll
    for (int sn = 0; sn < 4; ++sn) {
        int nn = n0 + wn * 64 + sn * 16 + lr;
        float bn = bo[nn];
        #pragma unroll
        for (int sm = 0; sm < 2; ++sm) {
            #pragma unroll
            for (int r = 0; r < 4; ++r)
                out[(size_t)(m0 + wm * 32 + sm * 16 + lg * 4 + r) * EE + nn]
                    = acc[sm][sn][r] + bn;
        }
    }
}

// ---------------------------------------------------------------------------
extern "C" void kernel_launch(void* const* d_in, const int* in_sizes, int n_in,
                              void* d_out, int out_size, void* d_ws, size_t ws_size,
                              hipStream_t stream)
{
    const float* Q  = (const float*)d_in[0];
    const float* K  = (const float*)d_in[1];
    const float* V  = (const float*)d_in[2];
    const float* Wq = (const float*)d_in[3];
    const float* Wk = (const float*)d_in[4];
    const float* Wv = (const float*)d_in[5];
    const float* Wo = (const float*)d_in[6];
    const float* bo = (const float*)d_in[7];
    float* out = (float*)d_out;

    const size_t NSE = (size_t)NB * SS * EE;   // 4.19M elements
    _Float16* Qp = (_Float16*)d_ws;  // [nh][s][d] pre-scaled   8.4 MB
    _Float16* Kp = Qp + NSE;         // [nh][s][d]              8.4 MB
    _Float16* Vt = Kp + NSE;         // [nh][d][s] transposed   8.4 MB
    _Float16* Of = Vt + NSE;         // [n][s][e] f16           8.4 MB
    _Float16* Wf = Of + NSE;         // [1024][1024] f16        2.1 MB (~36 MB)

    proj_kernel<<<1024, 256, 0, stream>>>(Q, K, V, Wq, Wk, Wv, Wo, Qp, Kp, Vt, Wf);
    attn_kernel<<<512, 256, 0, stream>>>(Qp, Kp, Vt, Of);   // 32 nh x 16 qt
    oproj_kernel<<<512, 256, 0, stream>>>(Of, Wf, bo, out);
}

// Round 6
// 202.425 us; speedup vs baseline: 1.1901x; 1.0052x over previous
//
#include <hip/hip_runtime.h>
#include <hip/hip_bf16.h>

// Problem constants
#define NB 2
#define SS 2048
#define EE 1024
#define HH 16
#define DD 64
#define NHD (NB*HH)   // 32 (n,h) pairs
#define KT 64         // keys per flash tile

// fold softmax scale (1/sqrt(1024)) and log2(e) into Q' so P = exp2(S')
#define QSCALE 0.04508422002777998f

typedef _Float16 half8 __attribute__((ext_vector_type(8)));
typedef float floatx4 __attribute__((ext_vector_type(4)));
typedef float floatx16 __attribute__((ext_vector_type(16)));

__device__ __forceinline__ half8 cvt8(const float* p) {
    float4 x = *(const float4*)p;
    float4 y = *(const float4*)(p + 4);
    half8 h = { (_Float16)x.x, (_Float16)x.y, (_Float16)x.z, (_Float16)x.w,
                (_Float16)y.x, (_Float16)y.y, (_Float16)y.z, (_Float16)y.w };
    return h;
}

// packed f32x2 -> f16x2 (RTZ) returning raw u32
__device__ __forceinline__ unsigned int pkrtz_u32(float a, float b) {
    return __builtin_bit_cast(unsigned int, __builtin_amdgcn_cvt_pkrtz(a, b));
}

// XOR-swizzled index (in halves) for [R][64-half] f16 LDS tiles (R<=128).
// 16B groups: group' = group ^ (row&7). Keeps b128 alignment (r13-verified).
__device__ __forceinline__ int swz64(int row, int colh) {
    return (row << 6) + ((((colh >> 3) ^ (row & 7)) << 3) | (colh & 7));
}

// ---------------------------------------------------------------------------
// Kernel 1 (r17): QKV projection via MFMA + absorbed Wo f32->f16.
// r13 proved scattered 2B stores are expensive (Vt fix: -17us). Qp/Kp were
// still stored as 2B scatters (32 instrs/thread, 4x32B partial-line txns
// each). r17: ALL outputs route through the swizzled LDS tile and store
// fully-coalesced 128B lines (4 store instrs/thread/tensor, 1KB/instr).
// Outputs: Q' f16 [nh][s][d] pre-scaled, K' f16 [nh][s][d], V' f16 [nh][d][s],
//          Wf f16 [1024][1024].
// ---------------------------------------------------------------------------
__global__ __launch_bounds__(256) void proj_kernel(
    const float* __restrict__ Q, const float* __restrict__ K, const float* __restrict__ V,
    const float* __restrict__ Wq, const float* __restrict__ Wk, const float* __restrict__ Wv,
    const float* __restrict__ Wo,
    _Float16* __restrict__ Qp, _Float16* __restrict__ Kp, _Float16* __restrict__ Vt,
    _Float16* __restrict__ Wf)
{
    int t = threadIdx.x, lane = t & 63, wid = t >> 6;
    int lr = lane & 15, lg = lane >> 4;
    int b = blockIdx.x;             // 0..1023
    int nh = b >> 5, st = b & 31;   // head-pair, s-tile (64 rows)
    int n = nh >> 4, h = nh & 15;

    // absorbed wconv: 128 threads x 8 elems = 1KB of Wo per block
    if (t < 128) {
        int i = b * 1024 + t * 8;
        *(half8*)(Wf + i) = cvt8(Wo + i);
    }

    __shared__ __align__(16) _Float16 vt[64 * 64];   // 8 KB, swizzled

    // A-fragment rows: s = st*64 + wid*16 + lr  (m = lane&15)
    const size_t xoff = ((size_t)n * SS + st * 64 + wid * 16 + lr) * EE
                        + (size_t)h * DD + lg * 8;

    // coalesced output map: thread t covers row t>>2, 2x16B at col (t&3)*16
    int orow = t >> 2, ocol = (t & 3) * 16;
    _Float16* qdst = Qp + ((size_t)nh * SS + st * 64 + orow) * DD + ocol;
    _Float16* kdst = Kp + ((size_t)nh * SS + st * 64 + orow) * DD + ocol;
    _Float16* vdst = Vt + ((size_t)nh * DD + orow) * SS + st * 64 + ocol;

    const float* tens[3] = {Q, K, V};
    const float* wts[3]  = {Wq, Wk, Wv};

    #pragma unroll
    for (int x = 0; x < 3; ++x) {
        const float* Xr = tens[x] + xoff;
        half8 a0 = cvt8(Xr);
        half8 a1 = cvt8(Xr + 32);
        floatx4 acc[4];
        #pragma unroll
        for (int ns = 0; ns < 4; ++ns) {
            const float* Wr = wts[x] + (size_t)(ns * 16 + lr) * DD + lg * 8;
            half8 b0 = cvt8(Wr);
            half8 b1 = cvt8(Wr + 32);
            floatx4 c = (floatx4){0.f, 0.f, 0.f, 0.f};
            c = __builtin_amdgcn_mfma_f32_16x16x32_f16(a0, b0, c, 0, 0, 0);
            c = __builtin_amdgcn_mfma_f32_16x16x32_f16(a1, b1, c, 0, 0, 0);
            acc[ns] = c;
        }
        if (x) __syncthreads();   // previous pass's vt reads done
        if (x < 2) {
            // Q/K: vt[s_local][d], s_local = wid*16+lg*4+r, d = ns*16+lr
            float s = (x == 0) ? QSCALE : 1.0f;
            #pragma unroll
            for (int ns = 0; ns < 4; ++ns)
                #pragma unroll
                for (int r = 0; r < 4; ++r)
                    vt[swz64(wid * 16 + lg * 4 + r, ns * 16 + lr)]
                        = (_Float16)(acc[ns][r] * s);
        } else {
            // V transpose: vt[d][s_local]
            #pragma unroll
            for (int ns = 0; ns < 4; ++ns)
                #pragma unroll
                for (int r = 0; r < 4; ++r)
                    vt[swz64(ns * 16 + lr, wid * 16 + lg * 4 + r)]
                        = (_Float16)(acc[ns][r]);
        }
        __syncthreads();
        _Float16* dst = (x == 0) ? qdst : (x == 1) ? kdst : vdst;
        *(half8*)dst       = *(const half8*)(&vt[swz64(orow, ocol)]);
        *(half8*)(dst + 8) = *(const half8*)(&vt[swz64(orow, ocol + 8)]);
    }
}

// ---------------------------------------------------------------------------
// Kernel 2 (r17): flash MFMA attention, 32x32 MFMA + in-register P (r16),
// + coalesced Of epilogue: O-tile staged into the dead kbuf (16KB) and
// stored as full 128B lines (4 b128/thread) instead of 32x 2B scatters.
// r16 post-mortem: attn ~72us with MfmaUtil 24 / VALU 56 / LDS all below
// wall -> latency/serialization regime; epilogue scatter is the remaining
// mechanistic waste.
// 32x32 frag maps (r16-verified): A/B[m][k]: m=lane&31, k=(lane>>5)*8+j.
// C/D: col=lane&31, row=(r&3)+8*(r>>2)+4*(lane>>5).
// GRID: 512 = 32 nh x 16 q-tiles (128 rows). LDS 32KB -> 2 blocks/CU.
// ---------------------------------------------------------------------------
__global__ __launch_bounds__(256, 2) void attn_kernel(
    const _Float16* __restrict__ Qp, const _Float16* __restrict__ Kp,
    const _Float16* __restrict__ Vt, _Float16* __restrict__ Of)
{
    int b = blockIdx.x;                  // 0..511
    int slot = b >> 3;                   // 0..63
    int nh = (b & 7) * 4 + (slot & 3);   // XCD swizzle: 4 heads per XCD in L2
    int qt = slot >> 2;                  // 0..15 (128-row q tile)
    int n = nh >> 4, h = nh & 15;
    int t = threadIdx.x;
    int lane = t & 63, wid = t >> 6;
    int l31 = lane & 31, h5 = lane >> 5;

    __shared__ __align__(16) _Float16 kbuf[2][KT * DD];   // 2 x 8 KB, swizzled
    __shared__ __align__(16) _Float16 vbuf[2][DD * KT];   // 2 x 8 KB, swizzled

    const _Float16* Kb = Kp + (size_t)nh * SS * DD;
    const _Float16* Vb = Vt + (size_t)nh * DD * SS;

    // Q B-fragments, loaded once: n=q=l31 (row), k=d = c*16 + h5*8 + j
    const _Float16* Qb = Qp + ((size_t)nh * SS + qt * 128 + wid * 32 + l31) * DD;
    half8 qf[4];
    #pragma unroll
    for (int c = 0; c < 4; ++c)
        qf[c] = *(const half8*)(Qb + c * 16 + h5 * 8);

    // ones B-fragment for the row-sum MFMA
    half8 ones = { (_Float16)1.f, (_Float16)1.f, (_Float16)1.f, (_Float16)1.f,
                   (_Float16)1.f, (_Float16)1.f, (_Float16)1.f, (_Float16)1.f };

    // staging map: slot s in [0,512): row = s>>3, colg = s&7 (8 half8s/row)
    int sr = t >> 3, sc = (t & 7) * 8;

    // ---- prologue: stage tile kb=0 into buffer 0
    {
        half8 k0 = *(const half8*)(Kb + (size_t)sr * DD + sc);
        half8 k1 = *(const half8*)(Kb + (size_t)(sr + 32) * DD + sc);
        half8 v0 = *(const half8*)(Vb + (size_t)sr * SS + sc);
        half8 v1 = *(const half8*)(Vb + (size_t)(sr + 32) * SS + sc);
        *(half8*)(&kbuf[0][swz64(sr, sc)]) = k0;
        *(half8*)(&kbuf[0][swz64(sr + 32, sc)]) = k1;
        *(half8*)(&vbuf[0][swz64(sr, sc)]) = v0;
        *(half8*)(&vbuf[0][swz64(sr + 32, sc)]) = v1;
    }
    __syncthreads();

    floatx16 oacc0 = {}, oacc1 = {};   // O for d-tiles 0,1
    floatx16 sacc  = {};               // row sums via ones-MFMA

    int p = 0;
    for (int kb = 0; kb < SS; kb += KT, p ^= 1) {
        // ---- issue global loads for tile t+1 (wrap at end: dummy, unused)
        int kn = (kb + KT) & (SS - 1);
        half8 sk0 = *(const half8*)(Kb + (size_t)(kn + sr) * DD + sc);
        half8 sk1 = *(const half8*)(Kb + (size_t)(kn + sr + 32) * DD + sc);
        half8 sv0 = *(const half8*)(Vb + (size_t)sr * SS + kn + sc);
        half8 sv1 = *(const half8*)(Vb + (size_t)(sr + 32) * SS + kn + sc);

        // ---- S^T = K Q^T for both 32-key subtiles: D[key][q]
        floatx16 s0 = {}, s1 = {};
        #pragma unroll
        for (int c = 0; c < 4; ++c) {
            half8 kf0 = *(const half8*)(&kbuf[p][swz64(l31,      c * 16 + h5 * 8)]);
            half8 kf1 = *(const half8*)(&kbuf[p][swz64(32 + l31, c * 16 + h5 * 8)]);
            s0 = __builtin_amdgcn_mfma_f32_32x32x16_f16(kf0, qf[c], s0, 0, 0, 0);
            s1 = __builtin_amdgcn_mfma_f32_32x32x16_f16(kf1, qf[c], s1, 0, 0, 0);
        }

        // ---- exp2 + pack + permlane redistribution -> PV A-fragments.
        half8 pf[4];
        #pragma unroll
        for (int kt2 = 0; kt2 < 2; ++kt2) {
            const floatx16& sv = kt2 ? s1 : s0;
            unsigned int w0, w1, w2, w3, w4, w5, w6, w7;
            {
                float e0 = exp2f(fminf(sv[0], 50.f)), e1 = exp2f(fminf(sv[1], 50.f));
                float e2 = exp2f(fminf(sv[2], 50.f)), e3 = exp2f(fminf(sv[3], 50.f));
                w0 = pkrtz_u32(e0, e1); w1 = pkrtz_u32(e2, e3);
            }
            {
                float e0 = exp2f(fminf(sv[4], 50.f)), e1 = exp2f(fminf(sv[5], 50.f));
                float e2 = exp2f(fminf(sv[6], 50.f)), e3 = exp2f(fminf(sv[7], 50.f));
                w2 = pkrtz_u32(e0, e1); w3 = pkrtz_u32(e2, e3);
            }
            {
                float e0 = exp2f(fminf(sv[8], 50.f)), e1 = exp2f(fminf(sv[9], 50.f));
                float e2 = exp2f(fminf(sv[10], 50.f)), e3 = exp2f(fminf(sv[11], 50.f));
                w4 = pkrtz_u32(e0, e1); w5 = pkrtz_u32(e2, e3);
            }
            {
                float e0 = exp2f(fminf(sv[12], 50.f)), e1 = exp2f(fminf(sv[13], 50.f));
                float e2 = exp2f(fminf(sv[14], 50.f)), e3 = exp2f(fminf(sv[15], 50.f));
                w6 = pkrtz_u32(e0, e1); w7 = pkrtz_u32(e2, e3);
            }
            asm("v_permlane32_swap_b32 %0, %1" : "+v"(w0), "+v"(w2));
            asm("v_permlane32_swap_b32 %0, %1" : "+v"(w1), "+v"(w3));
            asm("v_permlane32_swap_b32 %0, %1" : "+v"(w4), "+v"(w6));
            asm("v_permlane32_swap_b32 %0, %1" : "+v"(w5), "+v"(w7));
            uint4 ua = {w0, w1, w2, w3};
            uint4 ub = {w4, w5, w6, w7};
            pf[kt2 * 2 + 0] = __builtin_bit_cast(half8, ua);
            pf[kt2 * 2 + 1] = __builtin_bit_cast(half8, ub);
        }

        // ---- O += P V ; row-sum += P * ones. B = V[key][d] from vbuf[d][key].
        #pragma unroll
        for (int c = 0; c < 4; ++c) {
            half8 vf0 = *(const half8*)(&vbuf[p][swz64(l31,      c * 16 + h5 * 8)]);
            half8 vf1 = *(const half8*)(&vbuf[p][swz64(32 + l31, c * 16 + h5 * 8)]);
            oacc0 = __builtin_amdgcn_mfma_f32_32x32x16_f16(pf[c], vf0, oacc0, 0, 0, 0);
            oacc1 = __builtin_amdgcn_mfma_f32_32x32x16_f16(pf[c], vf1, oacc1, 0, 0, 0);
            sacc  = __builtin_amdgcn_mfma_f32_32x32x16_f16(pf[c], ones, sacc, 0, 0, 0);
        }

        // ---- write staged tile t+1 into the other buffer, then barrier
        *(half8*)(&kbuf[p ^ 1][swz64(sr, sc)]) = sk0;
        *(half8*)(&kbuf[p ^ 1][swz64(sr + 32, sc)]) = sk1;
        *(half8*)(&vbuf[p ^ 1][swz64(sr, sc)]) = sv0;
        *(half8*)(&vbuf[p ^ 1][swz64(sr + 32, sc)]) = sv1;
        __syncthreads();
    }

    // ---- normalize into the dead kbuf (16KB = [128][64] swizzled), then
    // store Of as full 128B lines (4 b128/thread) instead of 2B scatters.
    _Float16* obuf = (_Float16*)kbuf;
    #pragma unroll
    for (int r = 0; r < 16; ++r) {
        float linv = 1.f / sacc[r];
        int qrow = wid * 32 + (r & 3) + 8 * (r >> 2) + 4 * h5;
        obuf[swz64(qrow, l31)]      = (_Float16)(oacc0[r] * linv);
        obuf[swz64(qrow, 32 + l31)] = (_Float16)(oacc1[r] * linv);
    }
    __syncthreads();
    {
        int orow = t >> 2, ocol = (t & 3) * 16;
        _Float16* Ob = Of + ((size_t)n * SS + qt * 128) * EE + h * DD;
        #pragma unroll
        for (int g = 0; g < 2; ++g) {
            int rr = g * 64 + orow;
            *(half8*)(Ob + (size_t)rr * EE + ocol)
                = *(const half8*)(&obuf[swz64(rr, ocol)]);
            *(half8*)(Ob + (size_t)rr * EE + ocol + 8)
                = *(const half8*)(&obuf[swz64(rr, ocol + 8)]);
        }
    }
}

// ---------------------------------------------------------------------------
// Kernel 3 (r14, unchanged): out = O @ Wo.T + bo, 64x128-tile MFMA GEMM.
// 512 blocks = 2 blocks/CU; XCD swizzle pins Of m-tile per XCD L2.
// ---------------------------------------------------------------------------
__global__ __launch_bounds__(256, 2) void oproj_kernel(
    const _Float16* __restrict__ Of, const _Float16* __restrict__ Wf,
    const float* __restrict__ bo, float* __restrict__ out)
{
    int b = blockIdx.x;             // 0..511
    int mb = b & 63, nb = b >> 6;   // XCD = b%8 = mb%8 -> Of tile XCD-local
    int t = threadIdx.x, lane = t & 63, wid = t >> 6;
    int wm = wid >> 1, wn = wid & 1;
    int lr = lane & 15, lg = lane >> 4;
    int m0 = mb * 64, n0 = nb * 128;

    __shared__ __align__(16) _Float16 As[2][64][72];    // 2 x 9 KB
    __shared__ __align__(16) _Float16 Bs[2][128][72];   // 2 x 18 KB

    // staging maps: A: thread t covers row t>>2, 2 half8s at col (t&3)*16.
    //               B: thread t covers row t>>1, 4 half8s at col (t&1)*32.
    int arow = t >> 2, acol = (t & 3) * 16;
    int brow = t >> 1, bcol = (t & 1) * 32;
    const _Float16* Ag = Of + (size_t)(m0 + arow) * EE + acol;
    const _Float16* Bg = Wf + (size_t)(n0 + brow) * EE + bcol;

    floatx4 acc[2][4];
    #pragma unroll
    for (int sm = 0; sm < 2; ++sm)
        #pragma unroll
        for (int sn = 0; sn < 4; ++sn) acc[sm][sn] = (floatx4){0.f, 0.f, 0.f, 0.f};

    // ---- prologue: stage kb=0 into buffer 0
    #pragma unroll
    for (int j = 0; j < 2; ++j)
        *(half8*)(&As[0][arow][acol + j * 8]) = *(const half8*)(Ag + j * 8);
    #pragma unroll
    for (int j = 0; j < 4; ++j)
        *(half8*)(&Bs[0][brow][bcol + j * 8]) = *(const half8*)(Bg + j * 8);
    __syncthreads();

    int p = 0;
    for (int kb = 0; kb < EE; kb += 64, p ^= 1) {
        int kn = kb + 64;
        // ---- issue next chunk's global loads
        half8 sa[2], sb[4];
        if (kn < EE) {
            #pragma unroll
            for (int j = 0; j < 2; ++j) sa[j] = *(const half8*)(Ag + kn + j * 8);
            #pragma unroll
            for (int j = 0; j < 4; ++j) sb[j] = *(const half8*)(Bg + kn + j * 8);
        }
        // ---- compute on buffer p: 2 k-subchunks of 32
        #pragma unroll
        for (int kk = 0; kk < 2; ++kk) {
            half8 af[2], bf[4];
            #pragma unroll
            for (int s = 0; s < 2; ++s)
                af[s] = *(const half8*)(&As[p][wm * 32 + s * 16 + lr][kk * 32 + lg * 8]);
            #pragma unroll
            for (int s = 0; s < 4; ++s)
                bf[s] = *(const half8*)(&Bs[p][wn * 64 + s * 16 + lr][kk * 32 + lg * 8]);
            #pragma unroll
            for (int sm = 0; sm < 2; ++sm)
                #pragma unroll
                for (int sn = 0; sn < 4; ++sn)
                    acc[sm][sn] = __builtin_amdgcn_mfma_f32_16x16x32_f16(
                        af[sm], bf[sn], acc[sm][sn], 0, 0, 0);
        }
        // ---- write staged chunk into the other buffer
        if (kn < EE) {
            #pragma unroll
            for (int j = 0; j < 2; ++j)
                *(half8*)(&As[p ^ 1][arow][acol + j * 8]) = sa[j];
            #pragma unroll
            for (int j = 0; j < 4; ++j)
                *(half8*)(&Bs[p ^ 1][brow][bcol + j * 8]) = sb[j];
        }
        __syncthreads();
    }

    // ---- epilogue: C/D col = lr (n), row = lg*4+r (m)
    #pragma unroll
    for (int sn = 0; sn < 4; ++sn) {
        int nn = n0 + wn * 64 + sn * 16 + lr;
        float bn = bo[nn];
        #pragma unroll
        for (int sm = 0; sm < 2; ++sm) {
            #pragma unroll
            for (int r = 0; r < 4; ++r)
                out[(size_t)(m0 + wm * 32 + sm * 16 + lg * 4 + r) * EE + nn]
                    = acc[sm][sn][r] + bn;
        }
    }
}

// ---------------------------------------------------------------------------
extern "C" void kernel_launch(void* const* d_in, const int* in_sizes, int n_in,
                              void* d_out, int out_size, void* d_ws, size_t ws_size,
                              hipStream_t stream)
{
    const float* Q  = (const float*)d_in[0];
    const float* K  = (const float*)d_in[1];
    const float* V  = (const float*)d_in[2];
    const float* Wq = (const float*)d_in[3];
    const float* Wk = (const float*)d_in[4];
    const float* Wv = (const float*)d_in[5];
    const float* Wo = (const float*)d_in[6];
    const float* bo = (const float*)d_in[7];
    float* out = (float*)d_out;

    const size_t NSE = (size_t)NB * SS * EE;   // 4.19M elements
    _Float16* Qp = (_Float16*)d_ws;  // [nh][s][d] pre-scaled   8.4 MB
    _Float16* Kp = Qp + NSE;         // [nh][s][d]              8.4 MB
    _Float16* Vt = Kp + NSE;         // [nh][d][s] transposed   8.4 MB
    _Float16* Of = Vt + NSE;         // [n][s][e] f16           8.4 MB
    _Float16* Wf = Of + NSE;         // [1024][1024] f16        2.1 MB (~36 MB)

    proj_kernel<<<1024, 256, 0, stream>>>(Q, K, V, Wq, Wk, Wv, Wo, Qp, Kp, Vt, Wf);
    attn_kernel<<<512, 256, 0, stream>>>(Qp, Kp, Vt, Of);   // 32 nh x 16 qt
    oproj_kernel<<<512, 256, 0, stream>>>(Of, Wf, bo, out);
}